// Round 10
// baseline (431.347 us; speedup 1.0000x reference)
//
#include <hip/hip_runtime.h>

#define ACT 2026
#define NEGV -1.0e9f

typedef short short8 __attribute__((ext_vector_type(8)));
typedef float f32x4 __attribute__((ext_vector_type(4)));

__device__ __forceinline__ unsigned f2bf(float f) {
  unsigned u = __float_as_uint(f);
  return (u + 0x7FFFu + ((u >> 16) & 1u)) >> 16;   // RNE f32->bf16
}

__device__ __forceinline__ unsigned cvtpk(float lo, float hi) {
  unsigned r;
  asm("v_cvt_pk_bf16_f32 %0, %1, %2" : "=v"(r) : "v"(lo), "v"(hi));
  return r;
}

// ---------------------------------------------------------------------------
// prep kernel: fragment-major bf16 images of conv_w and the 25-row head panel
// ---------------------------------------------------------------------------
__global__ void prep_w_kernel(const float* __restrict__ conv_w,
                              const float* __restrict__ pos_w,
                              const float* __restrict__ patch_w,
                              unsigned short* __restrict__ wimg,
                              unsigned short* __restrict__ w2img) {
  int g = blockIdx.x * 256 + threadIdx.x;
  if (g < 8192) {
    int r = g & 15, gq = (g >> 4) & 3, mtg = (g >> 6) & 15, ks = g >> 10;
    const float* src = conv_w + (mtg * 16 + r) * 256 + ks * 32 + gq * 8;
    unsigned v0 = f2bf(src[0]) | (f2bf(src[1]) << 16);
    unsigned v1 = f2bf(src[2]) | (f2bf(src[3]) << 16);
    unsigned v2 = f2bf(src[4]) | (f2bf(src[5]) << 16);
    unsigned v3 = f2bf(src[6]) | (f2bf(src[7]) << 16);
    uint4 q; q.x = v0; q.y = v1; q.z = v2; q.w = v3;
    *(uint4*)(wimg + g * 8) = q;
  } else if (g < 9216) {
    int g2 = g - 8192;
    int r = g2 & 15, gq = (g2 >> 4) & 3, mt = (g2 >> 6) & 1, ks2 = g2 >> 7;
    int m2 = mt * 16 + r;
    int o0 = ks2 * 32 + gq * 8;
    unsigned short v[8];
#pragma unroll
    for (int e = 0; e < 8; ++e) {
      float f = 0.f;
      if (m2 < 24) f = pos_w[m2 * 256 + o0 + e];
      else if (m2 == 24) f = patch_w[o0 + e];
      v[e] = (unsigned short)f2bf(f);
    }
    uint4 q;
    q.x = (unsigned)v[0] | ((unsigned)v[1] << 16);
    q.y = (unsigned)v[2] | ((unsigned)v[3] << 16);
    q.z = (unsigned)v[4] | ((unsigned)v[5] << 16);
    q.w = (unsigned)v[6] | ((unsigned)v[7] << 16);
    *(uint4*)(w2img + g2 * 8) = q;
  }
}

// ---------------------------------------------------------------------------
// main fused kernel: 512 blocks x 512 threads (8 waves); each block = 8 rows,
// row-pipelined: row r+1's x-gather issues under row r's tail phases.
// ---------------------------------------------------------------------------
__global__ __launch_bounds__(512, 4)
void policy_main(const float* __restrict__ x,
                 const int* __restrict__ am,
                 const unsigned short* __restrict__ wimg,
                 const unsigned short* __restrict__ w2img,
                 const float* __restrict__ bn_gamma, const float* __restrict__ bn_beta,
                 const float* __restrict__ bn_mean, const float* __restrict__ bn_var,
                 const float* __restrict__ type_w, const float* __restrict__ type_b,
                 const float* __restrict__ patch_b,
                 const float* __restrict__ slot_w, const float* __restrict__ slot_b,
                 const float* __restrict__ orient_w, const float* __restrict__ orient_b,
                 const float* __restrict__ pos_b,
                 float* __restrict__ out)
{
  // Time-unioned region (49152 B) per row iteration:
  //   bfimg[8][6144] -> pT (49152) -> s_out2 (13312); cycle repeats per row.
  __shared__ __align__(16) char s_big[49152];
  __shared__ __align__(16) float s_scale[256];
  __shared__ __align__(16) float s_bias[256];
  __shared__ __align__(16) float s_pmean[256];
  __shared__ float s_part[240];
  __shared__ float s_hl[30];
  __shared__ float s_tlp[3], s_slp[3], s_olp[24];
  __shared__ int s_omask[24];
  __shared__ int s_misc[6];

  char* bfimg = s_big;
  unsigned short* pT = (unsigned short*)s_big;
  float* s_out2 = (float*)s_big;

  const int tid = threadIdx.x;
  const int w  = tid >> 6;     // wave 0..7
  const int l  = tid & 63;
  const int b0 = blockIdx.x * 8;

  if (tid < 256) { // BN folded scale/bias — once per block (8 rows)
    float sc = bn_gamma[tid] * rsqrtf(bn_var[tid] + 1e-5f);
    s_scale[tid] = sc;
    s_bias[tid]  = bn_beta[tid] - bn_mean[tid] * sc;
  }

  const int kg = l >> 4;   // MFMA k-group 0..3
  const int kr = l & 15;   // MFMA row/col lane 0..15
  const int g4 = kg * 4;
  const int fragoff = (kr * 4 + kg) * 16;
  const int mt  = w & 1;
  const int ntb = (w >> 1) * 3;

  // Row-independent gather geometry (R9, incl. the hw<=80 bounds clamp).
  int srcoff[6], dof[6];
  {
    const int pkg = l & 3;
    const int pkr = (l >> 2) & 15;
#pragma unroll
    for (int j = 0; j < 6; ++j) {
      int ksnt = j * 8 + w;                // wave-uniform (ks,nt)
      int ks = ksnt / 6, nt = ksnt % 6;
      int hwj = nt * 16 + pkr;
      if (hwj > 80) hwj = 80;              // in-bounds clamp (dup of col 80)
      srcoff[j] = (ks * 32 + pkg * 8) * 81 + hwj;
      dof[j]    = ks * 6144 + nt * 1024 + (pkr * 4 + pkg) * 16;
    }
  }

  float fb[6][8];
  auto GATHER = [&](int row) {             // 48 loads, all in flight
    const float* xb = x + (size_t)row * (256 * 81);
#pragma unroll
    for (int j = 0; j < 6; ++j)
#pragma unroll
      for (int e = 0; e < 8; ++e)
        fb[j][e] = xb[srcoff[j] + e * 81];
  };

  auto LDA = [&](int ks, short8 (&d)[2]) {
    const unsigned short* ab = wimg + ks * 8192 + w * 1024 + kg * 128 + kr * 8;
    d[0] = *(const short8*)(ab);
    d[1] = *(const short8*)(ab + 512);
  };

  GATHER(b0);                              // row 0 prologue (only exposed gather)

  for (int r = 0; r < 8; ++r) {
    const int b = b0 + r;
    const int* amr = am + (size_t)b * ACT;

    __syncthreads();   // prev row's s_out2 reads done -> bfimg may overwrite

    // -------- P0: fb -> bfimg (bf16 B-frag image) --------------------------
#pragma unroll
    for (int j = 0; j < 6; ++j) {
      uint4 v;
      v.x = cvtpk(fb[j][0], fb[j][1]);
      v.y = cvtpk(fb[j][2], fb[j][3]);
      v.z = cvtpk(fb[j][4], fb[j][5]);
      v.w = cvtpk(fb[j][6], fb[j][7]);
      *(uint4*)(bfimg + dof[j]) = v;
    }
    __syncthreads();

    // -------- P1: K-loop, af depth-2 prefetch (3-buffer rotation) ----------
    f32x4 acc[2][6];
#pragma unroll
    for (int i = 0; i < 2; ++i)
#pragma unroll
      for (int j = 0; j < 6; ++j) {
        f32x4 z = {0.f, 0.f, 0.f, 0.f};
        acc[i][j] = z;
      }
    {
      short8 af0[2], af1[2], af2[2];
      LDA(0, af0); LDA(1, af1);
      auto STEP = [&](int k, short8 (&cur)[2], short8 (&nxt)[2]) {
        if (k + 2 < 8) LDA(k + 2, nxt);
        const char* bi = bfimg + k * 6144;
#pragma unroll
        for (int nt = 0; nt < 6; ++nt) {
          short8 bf = *(const short8*)(bi + nt * 1024 + fragoff);
          acc[0][nt] = __builtin_amdgcn_mfma_f32_16x16x32_bf16(cur[0], bf, acc[0][nt], 0, 0, 0);
          acc[1][nt] = __builtin_amdgcn_mfma_f32_16x16x32_bf16(cur[1], bf, acc[1][nt], 0, 0, 0);
        }
      };
      STEP(0, af0, af2); STEP(1, af1, af0);
      STEP(2, af2, af1); STEP(3, af0, af2);
      STEP(4, af1, af0); STEP(5, af2, af1);
      STEP(6, af0, af2); STEP(7, af1, af0);
    }
    __syncthreads();   // all waves done with bfimg; pT may overlay

    // -------- P2: BN+ReLU -> pT + p_mean -----------------------------------
#pragma unroll
    for (int mi = 0; mi < 2; ++mi) {
      int ob = w * 32 + mi * 16 + g4;
      float sc0 = s_scale[ob], sc1 = s_scale[ob + 1], sc2 = s_scale[ob + 2], sc3 = s_scale[ob + 3];
      float bi0 = s_bias[ob],  bi1 = s_bias[ob + 1],  bi2 = s_bias[ob + 2],  bi3 = s_bias[ob + 3];
      float vs0 = 0.f, vs1 = 0.f, vs2 = 0.f, vs3 = 0.f;
      int ks2 = ob >> 5;
      int j2  = (ob >> 3) & 3;
      int e0  = ob & 7;
      char* pbase = (char*)pT + ks2 * 6144 + j2 * 256 + kr * 16 + e0 * 2;
#pragma unroll
      for (int nt = 0; nt < 6; ++nt) {
        float v0 = fmaxf(acc[mi][nt][0] * sc0 + bi0, 0.f);
        float v1 = fmaxf(acc[mi][nt][1] * sc1 + bi1, 0.f);
        float v2 = fmaxf(acc[mi][nt][2] * sc2 + bi2, 0.f);
        float v3 = fmaxf(acc[mi][nt][3] * sc3 + bi3, 0.f);
        if (nt < 5 || kr == 0) { vs0 += v0; vs1 += v1; vs2 += v2; vs3 += v3; } // hw<=80
        uint2 pvv;
        pvv.x = cvtpk(v0, v1);
        pvv.y = cvtpk(v2, v3);
        *(uint2*)(pbase + nt * 1024) = pvv;
      }
      float vv[4] = {vs0, vs1, vs2, vs3};
#pragma unroll
      for (int i = 0; i < 4; ++i) {
        float s = vv[i];
        s += __shfl_xor(s, 1);
        s += __shfl_xor(s, 2);
        s += __shfl_xor(s, 4);
        s += __shfl_xor(s, 8);
        vv[i] = s;
      }
      if (kr == 0) {
        s_pmean[ob]     = vv[0] * (1.f / 81.f);
        s_pmean[ob + 1] = vv[1] * (1.f / 81.f);
        s_pmean[ob + 2] = vv[2] * (1.f / 81.f);
        s_pmean[ob + 3] = vv[3] * (1.f / 81.f);
      }
    }
    __syncthreads();   // pT + s_pmean visible

    // -------- P3: issue next row's gather; GEMM-2 | masks+heads ------------
    if (r < 7) GATHER(b0 + r + 1);         // in flight under P3..P5 phases

    f32x4 acc2[3];
#pragma unroll
    for (int t = 0; t < 3; ++t) { f32x4 z = {0.f, 0.f, 0.f, 0.f}; acc2[t] = z; }

    if (w < 4) {
#pragma unroll
      for (int ks2 = 0; ks2 < 8; ++ks2) {
        const unsigned short* ap = w2img + ((ks2 * 2 + mt) * 4 + kg) * 128 + kr * 8;
        short8 a2 = *(const short8*)ap;
#pragma unroll
        for (int t = 0; t < 3; ++t) {
          const short8* bp = (const short8*)((const char*)pT + ks2 * 6144 + (ntb + t) * 1024 + kg * 256 + kr * 16);
          acc2[t] = __builtin_amdgcn_mfma_f32_16x16x32_bf16(a2, *bp, acc2[t], 0, 0, 0);
        }
      }
    } else {
      for (int t = w - 4; t < 25; t += 4) {
        int off = (t < 24) ? (82 + t * 81) : 1;
        int v1 = amr[off + l];
        int v2 = (l < 17) ? amr[off + 64 + l] : 0;
        unsigned long long bal = __ballot((v1 | v2) != 0);
        if (l == 0) {
          int any = (bal != 0ULL) ? 1 : 0;
          if (t < 24) s_omask[t] = any; else s_misc[0] = any;
        }
      }
      int hh = tid - 256;
      if (hh < 240) {
        int h = hh >> 3, seg = hh & 7;
        const float* wp = (h < 3) ? (type_w + h * 256)
                        : (h < 6) ? (slot_w + (h - 3) * 256)
                                  : (orient_w + (h - 6) * 256);
        float p = 0.f;
        int base = seg * 32;
#pragma unroll 8
        for (int e = 0; e < 32; ++e) p += s_pmean[base + e] * wp[base + e];
        s_part[hh] = p;
      }
    }
    __syncthreads();   // pT reads done; s_part/s_omask/s_misc visible

    // -------- P4: s_out2 (overlays pT) + head combine ----------------------
    if (w < 4) {
#pragma unroll
      for (int t = 0; t < 3; ++t) {
        int hw = (ntb + t) * 16 + kr;
        int m2 = mt * 16 + g4;
#pragma unroll
        for (int i = 0; i < 4; ++i)
          s_out2[(m2 + i) * 104 + hw] = acc2[t][i];
      }
    }
    if (tid < 30) {
      float a = 0.f;
#pragma unroll
      for (int e = 0; e < 8; ++e) a += s_part[tid * 8 + e];
      a += (tid < 3) ? type_b[tid] : (tid < 6) ? slot_b[tid - 3] : orient_b[tid - 6];
      s_hl[tid] = a;
    }
    if (tid == 32) {
      int sa0 = 0, sa1 = 0, sa2 = 0;
#pragma unroll
      for (int rr = 0; rr < 8; ++rr) { sa0 |= s_omask[rr]; sa1 |= s_omask[8 + rr]; sa2 |= s_omask[16 + rr]; }
      s_misc[1] = sa0; s_misc[2] = sa1; s_misc[3] = sa2;
      s_misc[4] = sa0 | sa1 | sa2;
    }
    __syncthreads();

    // -------- P5: small masked log-softmaxes -------------------------------
    if (tid == 0) {          // type
      int mk0 = amr[0] > 0, mk1 = s_misc[0], mk2 = s_misc[4];
      float g0 = mk0 ? s_hl[0] : NEGV;
      float g1 = mk1 ? s_hl[1] : NEGV;
      float g2 = mk2 ? s_hl[2] : NEGV;
      float m = fmaxf(fmaxf(g0, g1), g2);
      float sum = __expf(g0 - m) + __expf(g1 - m) + __expf(g2 - m);
      float ls = m + __logf(sum);
      s_tlp[0] = fmaxf(g0 - ls, -100.f);
      s_tlp[1] = fmaxf(g1 - ls, -100.f);
      s_tlp[2] = fmaxf(g2 - ls, -100.f);
    } else if (tid == 1) {   // slot
      float g[3]; float m = -3.0e38f;
#pragma unroll
      for (int s = 0; s < 3; ++s) { g[s] = s_misc[1 + s] ? s_hl[3 + s] : NEGV; m = fmaxf(m, g[s]); }
      float sum = 0.f;
#pragma unroll
      for (int s = 0; s < 3; ++s) sum += __expf(g[s] - m);
      float ls = m + __logf(sum);
#pragma unroll
      for (int s = 0; s < 3; ++s) s_slp[s] = fmaxf(g[s] - ls, -100.f);
    } else if (tid >= 2 && tid < 5) {   // orient per slot
      int s = tid - 2;
      float g[8]; float m = -3.0e38f;
#pragma unroll
      for (int rr = 0; rr < 8; ++rr) { g[rr] = s_omask[s * 8 + rr] ? s_hl[6 + s * 8 + rr] : NEGV; m = fmaxf(m, g[rr]); }
      float sum = 0.f;
#pragma unroll
      for (int rr = 0; rr < 8; ++rr) sum += __expf(g[rr] - m);
      float ls = m + __logf(sum);
#pragma unroll
      for (int rr = 0; rr < 8; ++rr) s_olp[s * 8 + rr] = fmaxf(g[rr] - ls, -100.f);
    }
    __syncthreads();

    // -------- P6: 81-wide row softmaxes + joint write ----------------------
    float* ob_out = out + (size_t)b * ACT;
    for (int t = w; t < 25; t += 8) {
      int off = (t < 24) ? (82 + t * 81) : 1;
      float badd = (t < 24) ? pos_b[t] : patch_b[0];
      int a1 = amr[off + l];
      int a2v = (l < 17) ? amr[off + 64 + l] : 0;
      float lg1 = (a1 > 0) ? (s_out2[t * 104 + l] + badd) : NEGV;
      float lg2 = (l < 17 && a2v > 0) ? (s_out2[t * 104 + 64 + l] + badd) : NEGV;
      float mx = fmaxf(lg1, (l < 17) ? lg2 : -3.0e38f);
#pragma unroll
      for (int mm = 1; mm < 64; mm <<= 1) mx = fmaxf(mx, __shfl_xor(mx, mm));
      float sm = __expf(lg1 - mx) + ((l < 17) ? __expf(lg2 - mx) : 0.f);
#pragma unroll
      for (int mm = 1; mm < 64; mm <<= 1) sm += __shfl_xor(sm, mm);
      float lse = mx + __logf(sm);
      float lp1 = fmaxf(lg1 - lse, -100.f);
      float lp2 = fmaxf(lg2 - lse, -100.f);
      float addj; int obase;
      if (t < 24) { addj = s_tlp[2] + s_slp[t >> 3] + s_olp[t]; obase = 82 + t * 81; }
      else        { addj = s_tlp[1];                             obase = 1; }
      ob_out[obase + l] = addj + lp1;
      if (l < 17) ob_out[obase + 64 + l] = addj + lp2;
      if (t == 24 && l == 0) ob_out[0] = s_tlp[0];
    }
  }
}

// ---------------------------------------------------------------------------
extern "C" void kernel_launch(void* const* d_in, const int* in_sizes, int n_in,
                              void* d_out, int out_size, void* d_ws, size_t ws_size,
                              hipStream_t stream) {
  (void)in_sizes; (void)n_in; (void)out_size; (void)ws_size;
  const float* x        = (const float*)d_in[0];
  const int*   amask    = (const int*)d_in[1];
  const float* conv_w   = (const float*)d_in[2];
  const float* bn_gamma = (const float*)d_in[3];
  const float* bn_beta  = (const float*)d_in[4];
  const float* bn_mean  = (const float*)d_in[5];
  const float* bn_var   = (const float*)d_in[6];
  const float* type_w   = (const float*)d_in[7];
  const float* type_b   = (const float*)d_in[8];
  const float* patch_w  = (const float*)d_in[9];
  const float* patch_b  = (const float*)d_in[10];
  const float* slot_w   = (const float*)d_in[11];
  const float* slot_b   = (const float*)d_in[12];
  const float* orient_w = (const float*)d_in[13];
  const float* orient_b = (const float*)d_in[14];
  const float* pos_w    = (const float*)d_in[15];
  const float* pos_b    = (const float*)d_in[16];
  float* outp = (float*)d_out;

  unsigned short* wimg  = (unsigned short*)d_ws;         // 131072 B
  unsigned short* w2img = wimg + 65536;                  // 16384 B

  prep_w_kernel<<<36, 256, 0, stream>>>(conv_w, pos_w, patch_w, wimg, w2img);
  policy_main<<<512, 512, 0, stream>>>(x, amask, wimg, w2img,
                                       bn_gamma, bn_beta, bn_mean, bn_var,
                                       type_w, type_b, patch_b,
                                       slot_w, slot_b, orient_w, orient_b,
                                       pos_b, outp);
}

// Round 12
// 193.876 us; speedup vs baseline: 2.2249x; 2.2249x over previous
//
#include <hip/hip_runtime.h>

#define ACT 2026
#define NEGV -1.0e9f

typedef short short8 __attribute__((ext_vector_type(8)));
typedef float f32x4 __attribute__((ext_vector_type(4)));

__device__ __forceinline__ unsigned f2bf(float f) {
  unsigned u = __float_as_uint(f);
  return (u + 0x7FFFu + ((u >> 16) & 1u)) >> 16;   // RNE f32->bf16
}

__device__ __forceinline__ unsigned cvtpk(float lo, float hi) {
  unsigned r;
  asm("v_cvt_pk_bf16_f32 %0, %1, %2" : "=v"(r) : "v"(lo), "v"(hi));
  return r;
}

#define GL16(gp, lp) __builtin_amdgcn_global_load_lds(                         \
    (const __attribute__((address_space(1))) void*)(gp),                       \
    (__attribute__((address_space(3))) void*)(lp), 16, 0, 0)

// ---------------------------------------------------------------------------
// prep kernel: fragment-major bf16 images of conv_w and the 25-row head panel
// ---------------------------------------------------------------------------
__global__ void prep_w_kernel(const float* __restrict__ conv_w,
                              const float* __restrict__ pos_w,
                              const float* __restrict__ patch_w,
                              unsigned short* __restrict__ wimg,
                              unsigned short* __restrict__ w2img) {
  int g = blockIdx.x * 256 + threadIdx.x;
  if (g < 8192) {
    int r = g & 15, gq = (g >> 4) & 3, mtg = (g >> 6) & 15, ks = g >> 10;
    const float* src = conv_w + (mtg * 16 + r) * 256 + ks * 32 + gq * 8;
    unsigned v0 = f2bf(src[0]) | (f2bf(src[1]) << 16);
    unsigned v1 = f2bf(src[2]) | (f2bf(src[3]) << 16);
    unsigned v2 = f2bf(src[4]) | (f2bf(src[5]) << 16);
    unsigned v3 = f2bf(src[6]) | (f2bf(src[7]) << 16);
    uint4 q; q.x = v0; q.y = v1; q.z = v2; q.w = v3;
    *(uint4*)(wimg + g * 8) = q;
  } else if (g < 9216) {
    int g2 = g - 8192;
    int r = g2 & 15, gq = (g2 >> 4) & 3, mt = (g2 >> 6) & 1, ks2 = g2 >> 7;
    int m2 = mt * 16 + r;
    int o0 = ks2 * 32 + gq * 8;
    unsigned short v[8];
#pragma unroll
    for (int e = 0; e < 8; ++e) {
      float f = 0.f;
      if (m2 < 24) f = pos_w[m2 * 256 + o0 + e];
      else if (m2 == 24) f = patch_w[o0 + e];
      v[e] = (unsigned short)f2bf(f);
    }
    uint4 q;
    q.x = (unsigned)v[0] | ((unsigned)v[1] << 16);
    q.y = (unsigned)v[2] | ((unsigned)v[3] << 16);
    q.z = (unsigned)v[4] | ((unsigned)v[5] << 16);
    q.w = (unsigned)v[6] | ((unsigned)v[7] << 16);
    *(uint4*)(w2img + g2 * 8) = q;
  }
}

// ---------------------------------------------------------------------------
// main fused kernel: 1 block = 1 batch row, 512 threads (8 waves), 2 blocks/CU
// K-loop: 4 supersteps (2 K-steps each), ONE barrier per superstep.
// ---------------------------------------------------------------------------
__global__ __launch_bounds__(512, 4)
void policy_main(const float* __restrict__ x,
                 const int* __restrict__ am,
                 const unsigned short* __restrict__ wimg,
                 const unsigned short* __restrict__ w2img,
                 const float* __restrict__ bn_gamma, const float* __restrict__ bn_beta,
                 const float* __restrict__ bn_mean, const float* __restrict__ bn_var,
                 const float* __restrict__ type_w, const float* __restrict__ type_b,
                 const float* __restrict__ patch_b,
                 const float* __restrict__ slot_w, const float* __restrict__ slot_b,
                 const float* __restrict__ orient_w, const float* __restrict__ orient_b,
                 const float* __restrict__ pos_b,
                 float* __restrict__ out)
{
  // Time-unioned region (66048 B):
  //   K-loop: f32buf[4] (4x10368 @ 0) + bfimg[4] (4x6144 @ 41472) = 66048
  //   then pT (49152 bf16), then s_out2 (13312 f32).
  __shared__ __align__(16) char s_big[66048];
  __shared__ __align__(16) float s_scale[256];
  __shared__ __align__(16) float s_bias[256];
  __shared__ __align__(16) float s_pmean[256];
  __shared__ float s_part[240];
  __shared__ float s_hl[30];
  __shared__ int s_omask[24];
  __shared__ int s_misc[6];

  char* f32buf = s_big;                    // [4][10368 B] raw x tiles
  char* bfimg  = s_big + 41472;            // [4][6144 B]  bf16 B-frag images
  unsigned short* pT = (unsigned short*)s_big;
  float* s_out2 = (float*)s_big;

  const int tid = threadIdx.x;
  const int w  = tid >> 6;     // wave 0..7
  const int l  = tid & 63;
  const int b  = blockIdx.x;
  const float* xb = x + (size_t)b * (256 * 81);

  if (tid < 256) { // BN folded scale/bias
    float sc = bn_gamma[tid] * rsqrtf(bn_var[tid] + 1e-5f);
    s_scale[tid] = sc;
    s_bias[tid]  = bn_beta[tid] - bn_mean[tid] * sc;
  }

  const int kg = l >> 4;   // MFMA k-group 0..3
  const int kr = l & 15;   // MFMA row/col lane 0..15
  const int g4 = kg * 4;
  const int fragoff = (kr * 4 + kg) * 16;

  f32x4 acc[2][6];
#pragma unroll
  for (int i = 0; i < 2; ++i)
#pragma unroll
    for (int j = 0; j < 6; ++j) {
      f32x4 z = {0.f, 0.f, 0.f, 0.f};
      acc[i][j] = z;
    }

  // x-tile ks: contiguous 10368B (648x16B) chunk -> LDS DMA.
  // 8 waves x 81 slots; two wave-uniform calls (64 + 64, overlap 47, benign dup).
  auto STAGE = [&](int ks) {
    const char* g = (const char*)xb + ks * 10368;
    char* lb = f32buf + (ks & 3) * 10368;
    int o1 = w * 81;
    int o2 = o1 + 17;
    GL16(g + (o1 + l) * 16, lb + o1 * 16);
    GL16(g + (o2 + l) * 16, lb + o2 * 16);
  };

  // One transpose chunk: f32 [c][hw] tile t, chunk q (of 384) -> bf16 B-frag.
  auto TRX = [&](int t, int q) {
    const float* src = (const float*)(f32buf + (t & 3) * 10368);
    char* dst = bfimg + (t & 3) * 6144;
    int nt_ = q >> 6, kr_ = (q >> 2) & 15, kg_ = q & 3;
    const float* s = src + kg_ * 648 + nt_ * 16 + kr_;
    uint4 v;
    v.x = cvtpk(s[0],   s[81]);
    v.y = cvtpk(s[162], s[243]);
    v.z = cvtpk(s[324], s[405]);
    v.w = cvtpk(s[486], s[567]);
    *(uint4*)(dst + q * 16) = v;
  };
  // Two tiles (768 chunks) spread over 512 threads, <=2 units each.
  auto TRANSPOSE2 = [&](int tA, int tB) {
    if (tid < 384) TRX(tA, tid);
    else           TRX(tB, tid - 384);
    if (tid < 256) TRX(tB, 128 + tid);
  };

  // ---- Prologue: stage tiles 0..3; build images 0,1 ------------------------
  STAGE(0); STAGE(1); STAGE(2); STAGE(3);             // FIFO: D0..D3 (8 ops)
  asm volatile("s_waitcnt vmcnt(4)" ::: "memory");    // own D0,D1 landed
  __builtin_amdgcn_s_barrier();                       // all waves' D0,D1 landed
  __builtin_amdgcn_sched_barrier(0);
  TRANSPOSE2(0, 1);
  asm volatile("s_waitcnt vmcnt(0)" ::: "memory");    // D2,D3 landed (for SS0's TRX)
  asm volatile("s_waitcnt lgkmcnt(0)" ::: "memory");  // images 0,1 visible
  __builtin_amdgcn_s_barrier();
  __builtin_amdgcn_sched_barrier(0);

  // Superstep s (tiles t0=2s, t1=2s+1):
  //   stage tiles {t0+4,t1+4} only for s<2 (tiles 4,5 then 6,7 — 8,9 DO NOT
  //   EXIST; R11 staged them and read past x's end -> page fault);
  //   transpose tiles {t0+2,t1+2} for s<3 (sources staged+drained 1 SS ago);
  //   MFMA sources bfimg[t0&3,t1&3] disjoint from transpose targets.
  auto SUPER = [&](int s) {
    const int t0 = 2 * s, t1 = t0 + 1;
    short8 af[4];
    {
      const unsigned short* ab0 = wimg + t0 * 8192 + w * 1024 + kg * 128 + kr * 8;
      const unsigned short* ab1 = wimg + t1 * 8192 + w * 1024 + kg * 128 + kr * 8;
      af[0] = *(const short8*)(ab0);
      af[1] = *(const short8*)(ab0 + 512);
      af[2] = *(const short8*)(ab1);
      af[3] = *(const short8*)(ab1 + 512);
    }
    __builtin_amdgcn_sched_barrier(0);      // pin af before the new DMAs
    if (s < 2) {
      STAGE(t0 + 4);
      STAGE(t1 + 4);
    }
    if (s < 3) TRANSPOSE2(t0 + 2, t1 + 2);
    const char* bi0 = bfimg + (t0 & 3) * 6144;
    const char* bi1 = bfimg + (t1 & 3) * 6144;
    __builtin_amdgcn_s_setprio(1);
#pragma unroll
    for (int nt = 0; nt < 6; ++nt) {
      short8 bf = *(const short8*)(bi0 + nt * 1024 + fragoff);
      acc[0][nt] = __builtin_amdgcn_mfma_f32_16x16x32_bf16(af[0], bf, acc[0][nt], 0, 0, 0);
      acc[1][nt] = __builtin_amdgcn_mfma_f32_16x16x32_bf16(af[1], bf, acc[1][nt], 0, 0, 0);
    }
#pragma unroll
    for (int nt = 0; nt < 6; ++nt) {
      short8 bf = *(const short8*)(bi1 + nt * 1024 + fragoff);
      acc[0][nt] = __builtin_amdgcn_mfma_f32_16x16x32_bf16(af[2], bf, acc[0][nt], 0, 0, 0);
      acc[1][nt] = __builtin_amdgcn_mfma_f32_16x16x32_bf16(af[3], bf, acc[1][nt], 0, 0, 0);
    }
    __builtin_amdgcn_s_setprio(0);
    if (s < 3) {
      asm volatile("s_waitcnt vmcnt(0)" ::: "memory");   // new DMAs landed
      asm volatile("s_waitcnt lgkmcnt(0)" ::: "memory"); // new images visible
      __builtin_amdgcn_s_barrier();
      __builtin_amdgcn_sched_barrier(0);
    } else {
      __syncthreads();                      // full fence before pT overlays
    }
  };

  SUPER(0); SUPER(1); SUPER(2); SUPER(3);

  // ---------------- BN+ReLU -> pT (bf16, GEMM-2 B-frag layout) + p_mean -----
#pragma unroll
  for (int mi = 0; mi < 2; ++mi) {
    int ob = w * 32 + mi * 16 + g4;
    float sc0 = s_scale[ob], sc1 = s_scale[ob + 1], sc2 = s_scale[ob + 2], sc3 = s_scale[ob + 3];
    float bi0 = s_bias[ob],  bi1 = s_bias[ob + 1],  bi2 = s_bias[ob + 2],  bi3 = s_bias[ob + 3];
    float vs0 = 0.f, vs1 = 0.f, vs2 = 0.f, vs3 = 0.f;
    int ks2 = ob >> 5;
    int j2  = (ob >> 3) & 3;
    int e0  = ob & 7;
    char* pbase = (char*)pT + ks2 * 6144 + j2 * 256 + kr * 16 + e0 * 2;
#pragma unroll
    for (int nt = 0; nt < 6; ++nt) {
      float v0 = fmaxf(acc[mi][nt][0] * sc0 + bi0, 0.f);
      float v1 = fmaxf(acc[mi][nt][1] * sc1 + bi1, 0.f);
      float v2 = fmaxf(acc[mi][nt][2] * sc2 + bi2, 0.f);
      float v3 = fmaxf(acc[mi][nt][3] * sc3 + bi3, 0.f);
      if (nt < 5 || kr == 0) { vs0 += v0; vs1 += v1; vs2 += v2; vs3 += v3; } // hw<=80
      uint2 pvv;
      pvv.x = cvtpk(v0, v1);
      pvv.y = cvtpk(v2, v3);
      *(uint2*)(pbase + nt * 1024) = pvv;
    }
    float vv[4] = {vs0, vs1, vs2, vs3};
#pragma unroll
    for (int i = 0; i < 4; ++i) {
      float s = vv[i];
      s += __shfl_xor(s, 1);
      s += __shfl_xor(s, 2);
      s += __shfl_xor(s, 4);
      s += __shfl_xor(s, 8);
      vv[i] = s;
    }
    if (kr == 0) {
      s_pmean[ob]     = vv[0] * (1.f / 81.f);
      s_pmean[ob + 1] = vv[1] * (1.f / 81.f);
      s_pmean[ob + 2] = vv[2] * (1.f / 81.f);
      s_pmean[ob + 3] = vv[3] * (1.f / 81.f);
    }
  }
  __syncthreads();   // pT + s_pmean visible

  // ---------------- Split phase: waves 0-3 GEMM-2 | waves 4-7 masks+heads ---
  const int* amr = am + (size_t)b * ACT;
  const int mt  = w & 1;
  const int ntb = (w >> 1) * 3;
  f32x4 acc2[3];
#pragma unroll
  for (int t = 0; t < 3; ++t) { f32x4 z = {0.f, 0.f, 0.f, 0.f}; acc2[t] = z; }

  if (w < 4) {
    // GEMM-2: out2[m2, hw] = w2 * p
#pragma unroll
    for (int ks2 = 0; ks2 < 8; ++ks2) {
      const unsigned short* ap = w2img + ((ks2 * 2 + mt) * 4 + kg) * 128 + kr * 8;
      short8 a2 = *(const short8*)ap;
#pragma unroll
      for (int t = 0; t < 3; ++t) {
        const short8* bp = (const short8*)((const char*)pT + ks2 * 6144 + (ntb + t) * 1024 + kg * 256 + kr * 16);
        acc2[t] = __builtin_amdgcn_mfma_f32_16x16x32_bf16(a2, *bp, acc2[t], 0, 0, 0);
      }
    }
  } else {
    // masks
    for (int t = w - 4; t < 25; t += 4) {
      int off = (t < 24) ? (82 + t * 81) : 1;
      int v1 = amr[off + l];
      int v2 = (l < 17) ? amr[off + 64 + l] : 0;
      unsigned long long bal = __ballot((v1 | v2) != 0);
      if (l == 0) {
        int any = (bal != 0ULL) ? 1 : 0;
        if (t < 24) s_omask[t] = any; else s_misc[0] = any;
      }
    }
    // head partial dots (30 heads x 8 segments = 240 units on waves 4-7)
    int hh = tid - 256;
    if (hh < 240) {
      int h = hh >> 3, seg = hh & 7;
      const float* wp = (h < 3) ? (type_w + h * 256)
                      : (h < 6) ? (slot_w + (h - 3) * 256)
                                : (orient_w + (h - 6) * 256);
      float p = 0.f;
      int base = seg * 32;
#pragma unroll 8
      for (int e = 0; e < 32; ++e) p += s_pmean[base + e] * wp[base + e];
      s_part[hh] = p;
    }
  }
  __syncthreads();   // pT reads done; s_part/s_omask/s_misc visible

  // -------- P4: s_out2 (overlays pT) + head combine + slot/buy any-masks ----
  if (w < 4) {
#pragma unroll
    for (int t = 0; t < 3; ++t) {
      int hw = (ntb + t) * 16 + kr;
      int m2 = mt * 16 + g4;
#pragma unroll
      for (int i = 0; i < 4; ++i)
        s_out2[(m2 + i) * 104 + hw] = acc2[t][i];
    }
  }
  if (tid < 30) {
    float a = 0.f;
#pragma unroll
    for (int e = 0; e < 8; ++e) a += s_part[tid * 8 + e];
    a += (tid < 3) ? type_b[tid] : (tid < 6) ? slot_b[tid - 3] : orient_b[tid - 6];
    s_hl[tid] = a;
  }
  if (tid == 32) {
    int sa0 = 0, sa1 = 0, sa2 = 0;
#pragma unroll
    for (int rr = 0; rr < 8; ++rr) { sa0 |= s_omask[rr]; sa1 |= s_omask[8 + rr]; sa2 |= s_omask[16 + rr]; }
    s_misc[1] = sa0; s_misc[2] = sa1; s_misc[3] = sa2;
    s_misc[4] = sa0 | sa1 | sa2;
  }
  __syncthreads();

  // -------- P6: per-thread small softmaxes (broadcast LDS reads) + 81-wide --
  float tlp0, tlp1, tlp2;
  {
    int mk0 = amr[0] > 0, mk1 = s_misc[0], mk2 = s_misc[4];
    float g0 = mk0 ? s_hl[0] : NEGV;
    float g1 = mk1 ? s_hl[1] : NEGV;
    float g2 = mk2 ? s_hl[2] : NEGV;
    float m = fmaxf(fmaxf(g0, g1), g2);
    float ls = m + __logf(__expf(g0 - m) + __expf(g1 - m) + __expf(g2 - m));
    tlp0 = fmaxf(g0 - ls, -100.f);
    tlp1 = fmaxf(g1 - ls, -100.f);
    tlp2 = fmaxf(g2 - ls, -100.f);
  }
  float slp[3];
  {
    float g[3]; float m = -3.0e38f;
#pragma unroll
    for (int s = 0; s < 3; ++s) { g[s] = s_misc[1 + s] ? s_hl[3 + s] : NEGV; m = fmaxf(m, g[s]); }
    float sum = 0.f;
#pragma unroll
    for (int s = 0; s < 3; ++s) sum += __expf(g[s] - m);
    float ls = m + __logf(sum);
#pragma unroll
    for (int s = 0; s < 3; ++s) slp[s] = fmaxf(g[s] - ls, -100.f);
  }

  float* ob_out = out + (size_t)b * ACT;
  for (int t = w; t < 25; t += 8) {
    int off = (t < 24) ? (82 + t * 81) : 1;
    float badd = (t < 24) ? pos_b[t] : patch_b[0];
    int a1 = amr[off + l];
    int a2v = (l < 17) ? amr[off + 64 + l] : 0;
    float lg1 = (a1 > 0) ? (s_out2[t * 104 + l] + badd) : NEGV;
    float lg2 = (l < 17 && a2v > 0) ? (s_out2[t * 104 + 64 + l] + badd) : NEGV;
    float mx = fmaxf(lg1, (l < 17) ? lg2 : -3.0e38f);
#pragma unroll
    for (int mm = 1; mm < 64; mm <<= 1) mx = fmaxf(mx, __shfl_xor(mx, mm));
    float sm = __expf(lg1 - mx) + ((l < 17) ? __expf(lg2 - mx) : 0.f);
#pragma unroll
    for (int mm = 1; mm < 64; mm <<= 1) sm += __shfl_xor(sm, mm);
    float lse = mx + __logf(sm);
    float lp1 = fmaxf(lg1 - lse, -100.f);
    float lp2 = fmaxf(lg2 - lse, -100.f);
    float addj; int obase;
    if (t < 24) {
      int sl = t >> 3;
      float g[8]; float m = -3.0e38f;
#pragma unroll
      for (int rr = 0; rr < 8; ++rr) {
        g[rr] = s_omask[sl * 8 + rr] ? s_hl[6 + sl * 8 + rr] : NEGV;
        m = fmaxf(m, g[rr]);
      }
      float sum = 0.f;
#pragma unroll
      for (int rr = 0; rr < 8; ++rr) sum += __expf(g[rr] - m);
      float ls = m + __logf(sum);
      float olp_t = fmaxf(g[t & 7] - ls, -100.f);
      addj = tlp2 + slp[sl] + olp_t;
      obase = 82 + t * 81;
    } else {
      addj = tlp1;
      obase = 1;
    }
    ob_out[obase + l] = addj + lp1;
    if (l < 17) ob_out[obase + 64 + l] = addj + lp2;
    if (t == 24 && l == 0) ob_out[0] = tlp0;
  }
}

// ---------------------------------------------------------------------------
extern "C" void kernel_launch(void* const* d_in, const int* in_sizes, int n_in,
                              void* d_out, int out_size, void* d_ws, size_t ws_size,
                              hipStream_t stream) {
  (void)in_sizes; (void)n_in; (void)out_size; (void)ws_size;
  const float* x        = (const float*)d_in[0];
  const int*   amask    = (const int*)d_in[1];
  const float* conv_w   = (const float*)d_in[2];
  const float* bn_gamma = (const float*)d_in[3];
  const float* bn_beta  = (const float*)d_in[4];
  const float* bn_mean  = (const float*)d_in[5];
  const float* bn_var   = (const float*)d_in[6];
  const float* type_w   = (const float*)d_in[7];
  const float* type_b   = (const float*)d_in[8];
  const float* patch_w  = (const float*)d_in[9];
  const float* patch_b  = (const float*)d_in[10];
  const float* slot_w   = (const float*)d_in[11];
  const float* slot_b   = (const float*)d_in[12];
  const float* orient_w = (const float*)d_in[13];
  const float* orient_b = (const float*)d_in[14];
  const float* pos_w    = (const float*)d_in[15];
  const float* pos_b    = (const float*)d_in[16];
  float* outp = (float*)d_out;

  unsigned short* wimg  = (unsigned short*)d_ws;         // 131072 B
  unsigned short* w2img = wimg + 65536;                  // 16384 B

  prep_w_kernel<<<36, 256, 0, stream>>>(conv_w, pos_w, patch_w, wimg, w2img);
  policy_main<<<4096, 512, 0, stream>>>(x, amask, wimg, w2img,
                                        bn_gamma, bn_beta, bn_mean, bn_var,
                                        type_w, type_b, patch_b,
                                        slot_w, slot_b, orient_w, orient_b,
                                        pos_b, outp);
}

// Round 13
// 186.330 us; speedup vs baseline: 2.3150x; 1.0405x over previous
//
#include <hip/hip_runtime.h>

#define ACT 2026
#define NEGV -1.0e9f

typedef short short8 __attribute__((ext_vector_type(8)));
typedef float f32x4 __attribute__((ext_vector_type(4)));

__device__ __forceinline__ unsigned f2bf(float f) {
  unsigned u = __float_as_uint(f);
  return (u + 0x7FFFu + ((u >> 16) & 1u)) >> 16;   // RNE f32->bf16
}

__device__ __forceinline__ unsigned cvtpk(float lo, float hi) {
  unsigned r;
  asm("v_cvt_pk_bf16_f32 %0, %1, %2" : "=v"(r) : "v"(lo), "v"(hi));
  return r;
}

#define GL16(gp, lp) __builtin_amdgcn_global_load_lds(                         \
    (const __attribute__((address_space(1))) void*)(gp),                       \
    (__attribute__((address_space(3))) void*)(lp), 16, 0, 0)

// ---------------------------------------------------------------------------
// prep kernel: fragment-major bf16 images of conv_w and the 25-row head panel
// ---------------------------------------------------------------------------
__global__ void prep_w_kernel(const float* __restrict__ conv_w,
                              const float* __restrict__ pos_w,
                              const float* __restrict__ patch_w,
                              unsigned short* __restrict__ wimg,
                              unsigned short* __restrict__ w2img) {
  int g = blockIdx.x * 256 + threadIdx.x;
  if (g < 8192) {
    int r = g & 15, gq = (g >> 4) & 3, mtg = (g >> 6) & 15, ks = g >> 10;
    const float* src = conv_w + (mtg * 16 + r) * 256 + ks * 32 + gq * 8;
    unsigned v0 = f2bf(src[0]) | (f2bf(src[1]) << 16);
    unsigned v1 = f2bf(src[2]) | (f2bf(src[3]) << 16);
    unsigned v2 = f2bf(src[4]) | (f2bf(src[5]) << 16);
    unsigned v3 = f2bf(src[6]) | (f2bf(src[7]) << 16);
    uint4 q; q.x = v0; q.y = v1; q.z = v2; q.w = v3;
    *(uint4*)(wimg + g * 8) = q;
  } else if (g < 9216) {
    int g2 = g - 8192;
    int r = g2 & 15, gq = (g2 >> 4) & 3, mt = (g2 >> 6) & 1, ks2 = g2 >> 7;
    int m2 = mt * 16 + r;
    int o0 = ks2 * 32 + gq * 8;
    unsigned short v[8];
#pragma unroll
    for (int e = 0; e < 8; ++e) {
      float f = 0.f;
      if (m2 < 24) f = pos_w[m2 * 256 + o0 + e];
      else if (m2 == 24) f = patch_w[o0 + e];
      v[e] = (unsigned short)f2bf(f);
    }
    uint4 q;
    q.x = (unsigned)v[0] | ((unsigned)v[1] << 16);
    q.y = (unsigned)v[2] | ((unsigned)v[3] << 16);
    q.z = (unsigned)v[4] | ((unsigned)v[5] << 16);
    q.w = (unsigned)v[6] | ((unsigned)v[7] << 16);
    *(uint4*)(w2img + g2 * 8) = q;
  }
}

// ---------------------------------------------------------------------------
// main fused kernel: 1 block = 1 batch row, 1024 threads (16 waves),
// 2 blocks/CU -> 8 waves/SIMD. Each wave owns 16 o's (acc = 24 regs).
// K-loop: 4 supersteps (2 K-steps each), ONE barrier per superstep.
// ---------------------------------------------------------------------------
__global__ __launch_bounds__(1024, 8)
void policy_main(const float* __restrict__ x,
                 const int* __restrict__ am,
                 const unsigned short* __restrict__ wimg,
                 const unsigned short* __restrict__ w2img,
                 const float* __restrict__ bn_gamma, const float* __restrict__ bn_beta,
                 const float* __restrict__ bn_mean, const float* __restrict__ bn_var,
                 const float* __restrict__ type_w, const float* __restrict__ type_b,
                 const float* __restrict__ patch_b,
                 const float* __restrict__ slot_w, const float* __restrict__ slot_b,
                 const float* __restrict__ orient_w, const float* __restrict__ orient_b,
                 const float* __restrict__ pos_b,
                 float* __restrict__ out)
{
  // Time-unioned region (66048 B):
  //   K-loop: f32buf[4] (4x10368 @ 0) + bfimg[4] (4x6144 @ 41472) = 66048
  //   then pT (49152 bf16), then s_out2 (13312 f32).
  __shared__ __align__(16) char s_big[66048];
  __shared__ __align__(16) float s_scale[256];
  __shared__ __align__(16) float s_bias[256];
  __shared__ __align__(16) float s_pmean[256];
  __shared__ float s_part[240];
  __shared__ float s_hl[30];
  __shared__ int s_omask[24];
  __shared__ int s_misc[6];

  char* f32buf = s_big;                    // [4][10368 B] raw x tiles
  char* bfimg  = s_big + 41472;            // [4][6144 B]  bf16 B-frag images
  unsigned short* pT = (unsigned short*)s_big;
  float* s_out2 = (float*)s_big;

  const int tid = threadIdx.x;
  const int w  = tid >> 6;     // wave 0..15
  const int l  = tid & 63;
  const int b  = blockIdx.x;
  const float* xb = x + (size_t)b * (256 * 81);

  if (tid < 256) { // BN folded scale/bias
    float sc = bn_gamma[tid] * rsqrtf(bn_var[tid] + 1e-5f);
    s_scale[tid] = sc;
    s_bias[tid]  = bn_beta[tid] - bn_mean[tid] * sc;
  }

  const int kg = l >> 4;   // MFMA k-group 0..3
  const int kr = l & 15;   // MFMA row/col lane 0..15
  const int g4 = kg * 4;
  const int fragoff = (kr * 4 + kg) * 16;

  f32x4 acc[6];            // one 16-o M-frag x 6 N-frags = 24 VGPR
#pragma unroll
  for (int j = 0; j < 6; ++j) {
    f32x4 z = {0.f, 0.f, 0.f, 0.f};
    acc[j] = z;
  }

  // x-tile ks: contiguous 10368B (648x16B) chunk -> LDS DMA; 1 DMA per thread
  // for tid<648 (partial-exec waves fine; vmcnt ledger is per-wave and all
  // in-loop waits drain to 0).
  auto STAGE = [&](int ks) {
    const char* g = (const char*)xb + ks * 10368;
    char* lb = f32buf + (ks & 3) * 10368;
    if (tid < 648) GL16(g + tid * 16, lb + tid * 16);
  };

  // One transpose chunk: f32 [c][hw] tile t, chunk q (of 384) -> bf16 B-frag.
  auto TRX = [&](int t, int q) {
    const float* src = (const float*)(f32buf + (t & 3) * 10368);
    char* dst = bfimg + (t & 3) * 6144;
    int nt_ = q >> 6, kr_ = (q >> 2) & 15, kg_ = q & 3;
    const float* s = src + kg_ * 648 + nt_ * 16 + kr_;
    uint4 v;
    v.x = cvtpk(s[0],   s[81]);
    v.y = cvtpk(s[162], s[243]);
    v.z = cvtpk(s[324], s[405]);
    v.w = cvtpk(s[486], s[567]);
    *(uint4*)(dst + q * 16) = v;
  };
  // Two tiles (768 chunks) over 1024 threads: 1 chunk each for tid<768.
  auto TRANSPOSE2 = [&](int tA, int tB) {
    if (tid < 384)      TRX(tA, tid);
    else if (tid < 768) TRX(tB, tid - 384);
  };

  // ---- Prologue: stage tiles 0..3; build images 0,1 ------------------------
  STAGE(0); STAGE(1); STAGE(2); STAGE(3);             // <=4 DMA per wave
  asm volatile("s_waitcnt vmcnt(2)" ::: "memory");    // own D0,D1 landed
  __builtin_amdgcn_s_barrier();                       // all waves' D0,D1 landed
  __builtin_amdgcn_sched_barrier(0);
  TRANSPOSE2(0, 1);
  asm volatile("s_waitcnt vmcnt(0)" ::: "memory");    // D2,D3 landed
  asm volatile("s_waitcnt lgkmcnt(0)" ::: "memory");  // images 0,1 visible
  __builtin_amdgcn_s_barrier();
  __builtin_amdgcn_sched_barrier(0);

  // Superstep s (tiles t0=2s, t1=2s+1): stage {t0+4,t1+4} only for s<2
  // (tiles 8,9 don't exist); transpose {t0+2,t1+2} for s<3 (staged+drained
  // one superstep earlier); MFMA sources disjoint from transpose targets.
  auto SUPER = [&](int s) {
    const int t0 = 2 * s, t1 = t0 + 1;
    short8 af0, af1;
    {
      const unsigned short* ab = wimg + w * 512 + kg * 128 + kr * 8;
      af0 = *(const short8*)(ab + t0 * 8192);
      af1 = *(const short8*)(ab + t1 * 8192);
    }
    __builtin_amdgcn_sched_barrier(0);      // pin af before the new DMAs
    if (s < 2) {
      STAGE(t0 + 4);
      STAGE(t1 + 4);
    }
    if (s < 3) TRANSPOSE2(t0 + 2, t1 + 2);
    const char* bi0 = bfimg + (t0 & 3) * 6144;
    const char* bi1 = bfimg + (t1 & 3) * 6144;
    __builtin_amdgcn_s_setprio(1);
#pragma unroll
    for (int nt = 0; nt < 6; ++nt) {
      short8 bf = *(const short8*)(bi0 + nt * 1024 + fragoff);
      acc[nt] = __builtin_amdgcn_mfma_f32_16x16x32_bf16(af0, bf, acc[nt], 0, 0, 0);
    }
#pragma unroll
    for (int nt = 0; nt < 6; ++nt) {
      short8 bf = *(const short8*)(bi1 + nt * 1024 + fragoff);
      acc[nt] = __builtin_amdgcn_mfma_f32_16x16x32_bf16(af1, bf, acc[nt], 0, 0, 0);
    }
    __builtin_amdgcn_s_setprio(0);
    if (s < 3) {
      asm volatile("s_waitcnt vmcnt(0)" ::: "memory");   // new DMAs landed
      asm volatile("s_waitcnt lgkmcnt(0)" ::: "memory"); // new images visible
      __builtin_amdgcn_s_barrier();
      __builtin_amdgcn_sched_barrier(0);
    } else {
      __syncthreads();                      // full fence before pT overlays
    }
  };

  SUPER(0); SUPER(1); SUPER(2); SUPER(3);

  // ---------------- BN+ReLU -> pT (bf16, GEMM-2 B-frag layout) + p_mean -----
  {
    int ob = w * 16 + g4;
    float sc0 = s_scale[ob], sc1 = s_scale[ob + 1], sc2 = s_scale[ob + 2], sc3 = s_scale[ob + 3];
    float bi0 = s_bias[ob],  bi1 = s_bias[ob + 1],  bi2 = s_bias[ob + 2],  bi3 = s_bias[ob + 3];
    float vs0 = 0.f, vs1 = 0.f, vs2 = 0.f, vs3 = 0.f;
    int ks2 = ob >> 5;
    int j2  = (ob >> 3) & 3;
    int e0  = ob & 7;
    char* pbase = (char*)pT + ks2 * 6144 + j2 * 256 + kr * 16 + e0 * 2;
#pragma unroll
    for (int nt = 0; nt < 6; ++nt) {
      float v0 = fmaxf(acc[nt][0] * sc0 + bi0, 0.f);
      float v1 = fmaxf(acc[nt][1] * sc1 + bi1, 0.f);
      float v2 = fmaxf(acc[nt][2] * sc2 + bi2, 0.f);
      float v3 = fmaxf(acc[nt][3] * sc3 + bi3, 0.f);
      if (nt < 5 || kr == 0) { vs0 += v0; vs1 += v1; vs2 += v2; vs3 += v3; } // hw<=80
      uint2 pvv;
      pvv.x = cvtpk(v0, v1);
      pvv.y = cvtpk(v2, v3);
      *(uint2*)(pbase + nt * 1024) = pvv;
    }
    float vv[4] = {vs0, vs1, vs2, vs3};
#pragma unroll
    for (int i = 0; i < 4; ++i) {
      float s = vv[i];
      s += __shfl_xor(s, 1);
      s += __shfl_xor(s, 2);
      s += __shfl_xor(s, 4);
      s += __shfl_xor(s, 8);
      vv[i] = s;
    }
    if (kr == 0) {
      s_pmean[ob]     = vv[0] * (1.f / 81.f);
      s_pmean[ob + 1] = vv[1] * (1.f / 81.f);
      s_pmean[ob + 2] = vv[2] * (1.f / 81.f);
      s_pmean[ob + 3] = vv[3] * (1.f / 81.f);
    }
  }
  __syncthreads();   // pT + s_pmean visible

  // ---------------- Split phase: waves 0-3 GEMM-2 | waves 4-7 masks+heads ---
  const int* amr = am + (size_t)b * ACT;
  const int mt  = w & 1;
  const int ntb = (w >> 1) * 3;
  f32x4 acc2[3];
#pragma unroll
  for (int t = 0; t < 3; ++t) { f32x4 z = {0.f, 0.f, 0.f, 0.f}; acc2[t] = z; }

  if (w < 4) {
    // GEMM-2: out2[m2, hw] = w2 * p
#pragma unroll
    for (int ks2 = 0; ks2 < 8; ++ks2) {
      const unsigned short* ap = w2img + ((ks2 * 2 + mt) * 4 + kg) * 128 + kr * 8;
      short8 a2 = *(const short8*)ap;
#pragma unroll
      for (int t = 0; t < 3; ++t) {
        const short8* bp = (const short8*)((const char*)pT + ks2 * 6144 + (ntb + t) * 1024 + kg * 256 + kr * 16);
        acc2[t] = __builtin_amdgcn_mfma_f32_16x16x32_bf16(a2, *bp, acc2[t], 0, 0, 0);
      }
    }
  } else if (w < 8) {
    // masks
    for (int t = w - 4; t < 25; t += 4) {
      int off = (t < 24) ? (82 + t * 81) : 1;
      int v1 = amr[off + l];
      int v2 = (l < 17) ? amr[off + 64 + l] : 0;
      unsigned long long bal = __ballot((v1 | v2) != 0);
      if (l == 0) {
        int any = (bal != 0ULL) ? 1 : 0;
        if (t < 24) s_omask[t] = any; else s_misc[0] = any;
      }
    }
    // head partial dots (30 heads x 8 segments = 240 units on waves 4-7)
    int hh = tid - 256;
    if (hh < 240) {
      int h = hh >> 3, seg = hh & 7;
      const float* wp = (h < 3) ? (type_w + h * 256)
                      : (h < 6) ? (slot_w + (h - 3) * 256)
                                : (orient_w + (h - 6) * 256);
      float p = 0.f;
      int base = seg * 32;
#pragma unroll 8
      for (int e = 0; e < 32; ++e) p += s_pmean[base + e] * wp[base + e];
      s_part[hh] = p;
    }
  }
  __syncthreads();   // pT reads done; s_part/s_omask/s_misc visible

  // -------- P4: s_out2 (overlays pT) + head combine + slot/buy any-masks ----
  if (w < 4) {
#pragma unroll
    for (int t = 0; t < 3; ++t) {
      int hw = (ntb + t) * 16 + kr;
      int m2 = mt * 16 + g4;
#pragma unroll
      for (int i = 0; i < 4; ++i)
        s_out2[(m2 + i) * 104 + hw] = acc2[t][i];
    }
  }
  if (tid < 30) {
    float a = 0.f;
#pragma unroll
    for (int e = 0; e < 8; ++e) a += s_part[tid * 8 + e];
    a += (tid < 3) ? type_b[tid] : (tid < 6) ? slot_b[tid - 3] : orient_b[tid - 6];
    s_hl[tid] = a;
  }
  if (tid == 32) {
    int sa0 = 0, sa1 = 0, sa2 = 0;
#pragma unroll
    for (int rr = 0; rr < 8; ++rr) { sa0 |= s_omask[rr]; sa1 |= s_omask[8 + rr]; sa2 |= s_omask[16 + rr]; }
    s_misc[1] = sa0; s_misc[2] = sa1; s_misc[3] = sa2;
    s_misc[4] = sa0 | sa1 | sa2;
  }
  __syncthreads();

  // -------- P6: per-thread small softmaxes (broadcast LDS reads) + 81-wide --
  float tlp0, tlp1, tlp2;
  {
    int mk0 = amr[0] > 0, mk1 = s_misc[0], mk2 = s_misc[4];
    float g0 = mk0 ? s_hl[0] : NEGV;
    float g1 = mk1 ? s_hl[1] : NEGV;
    float g2 = mk2 ? s_hl[2] : NEGV;
    float m = fmaxf(fmaxf(g0, g1), g2);
    float ls = m + __logf(__expf(g0 - m) + __expf(g1 - m) + __expf(g2 - m));
    tlp0 = fmaxf(g0 - ls, -100.f);
    tlp1 = fmaxf(g1 - ls, -100.f);
    tlp2 = fmaxf(g2 - ls, -100.f);
  }
  float slp[3];
  {
    float g[3]; float m = -3.0e38f;
#pragma unroll
    for (int s = 0; s < 3; ++s) { g[s] = s_misc[1 + s] ? s_hl[3 + s] : NEGV; m = fmaxf(m, g[s]); }
    float sum = 0.f;
#pragma unroll
    for (int s = 0; s < 3; ++s) sum += __expf(g[s] - m);
    float ls = m + __logf(sum);
#pragma unroll
    for (int s = 0; s < 3; ++s) slp[s] = fmaxf(g[s] - ls, -100.f);
  }

  float* ob_out = out + (size_t)b * ACT;
  for (int t = w; t < 25; t += 16) {
    int off = (t < 24) ? (82 + t * 81) : 1;
    float badd = (t < 24) ? pos_b[t] : patch_b[0];
    int a1 = amr[off + l];
    int a2v = (l < 17) ? amr[off + 64 + l] : 0;
    float lg1 = (a1 > 0) ? (s_out2[t * 104 + l] + badd) : NEGV;
    float lg2 = (l < 17 && a2v > 0) ? (s_out2[t * 104 + 64 + l] + badd) : NEGV;
    float mx = fmaxf(lg1, (l < 17) ? lg2 : -3.0e38f);
#pragma unroll
    for (int mm = 1; mm < 64; mm <<= 1) mx = fmaxf(mx, __shfl_xor(mx, mm));
    float sm = __expf(lg1 - mx) + ((l < 17) ? __expf(lg2 - mx) : 0.f);
#pragma unroll
    for (int mm = 1; mm < 64; mm <<= 1) sm += __shfl_xor(sm, mm);
    float lse = mx + __logf(sm);
    float lp1 = fmaxf(lg1 - lse, -100.f);
    float lp2 = fmaxf(lg2 - lse, -100.f);
    float addj; int obase;
    if (t < 24) {
      int sl = t >> 3;
      float g[8]; float m = -3.0e38f;
#pragma unroll
      for (int rr = 0; rr < 8; ++rr) {
        g[rr] = s_omask[sl * 8 + rr] ? s_hl[6 + sl * 8 + rr] : NEGV;
        m = fmaxf(m, g[rr]);
      }
      float sum = 0.f;
#pragma unroll
      for (int rr = 0; rr < 8; ++rr) sum += __expf(g[rr] - m);
      float ls = m + __logf(sum);
      float olp_t = fmaxf(g[t & 7] - ls, -100.f);
      addj = tlp2 + slp[sl] + olp_t;
      obase = 82 + t * 81;
    } else {
      addj = tlp1;
      obase = 1;
    }
    ob_out[obase + l] = addj + lp1;
    if (l < 17) ob_out[obase + 64 + l] = addj + lp2;
    if (t == 24 && l == 0) ob_out[0] = tlp0;
  }
}

// ---------------------------------------------------------------------------
extern "C" void kernel_launch(void* const* d_in, const int* in_sizes, int n_in,
                              void* d_out, int out_size, void* d_ws, size_t ws_size,
                              hipStream_t stream) {
  (void)in_sizes; (void)n_in; (void)out_size; (void)ws_size;
  const float* x        = (const float*)d_in[0];
  const int*   amask    = (const int*)d_in[1];
  const float* conv_w   = (const float*)d_in[2];
  const float* bn_gamma = (const float*)d_in[3];
  const float* bn_beta  = (const float*)d_in[4];
  const float* bn_mean  = (const float*)d_in[5];
  const float* bn_var   = (const float*)d_in[6];
  const float* type_w   = (const float*)d_in[7];
  const float* type_b   = (const float*)d_in[8];
  const float* patch_w  = (const float*)d_in[9];
  const float* patch_b  = (const float*)d_in[10];
  const float* slot_w   = (const float*)d_in[11];
  const float* slot_b   = (const float*)d_in[12];
  const float* orient_w = (const float*)d_in[13];
  const float* orient_b = (const float*)d_in[14];
  const float* pos_w    = (const float*)d_in[15];
  const float* pos_b    = (const float*)d_in[16];
  float* outp = (float*)d_out;

  unsigned short* wimg  = (unsigned short*)d_ws;         // 131072 B
  unsigned short* w2img = wimg + 65536;                  // 16384 B

  prep_w_kernel<<<36, 256, 0, stream>>>(conv_w, pos_w, patch_w, wimg, w2img);
  policy_main<<<4096, 1024, 0, stream>>>(x, amask, wimg, w2img,
                                         bn_gamma, bn_beta, bn_mean, bn_var,
                                         type_w, type_b, patch_b,
                                         slot_w, slot_b, orient_w, orient_b,
                                         pos_b, outp);
}

// Round 14
// 182.729 us; speedup vs baseline: 2.3606x; 1.0197x over previous
//
#include <hip/hip_runtime.h>

#define ACT 2026
#define NEGV -1.0e9f

typedef short short8 __attribute__((ext_vector_type(8)));
typedef float f32x4 __attribute__((ext_vector_type(4)));

__device__ __forceinline__ unsigned f2bf(float f) {
  unsigned u = __float_as_uint(f);
  return (u + 0x7FFFu + ((u >> 16) & 1u)) >> 16;   // RNE f32->bf16
}

__device__ __forceinline__ unsigned cvtpk(float lo, float hi) {
  unsigned r;
  asm("v_cvt_pk_bf16_f32 %0, %1, %2" : "=v"(r) : "v"(lo), "v"(hi));
  return r;
}

#define GL16(gp, lp) __builtin_amdgcn_global_load_lds(                         \
    (const __attribute__((address_space(1))) void*)(gp),                       \
    (__attribute__((address_space(3))) void*)(lp), 16, 0, 0)

// ---------------------------------------------------------------------------
// prep kernel: fragment-major bf16 images of conv_w and the 25-row head panel
// ---------------------------------------------------------------------------
__global__ void prep_w_kernel(const float* __restrict__ conv_w,
                              const float* __restrict__ pos_w,
                              const float* __restrict__ patch_w,
                              unsigned short* __restrict__ wimg,
                              unsigned short* __restrict__ w2img) {
  int g = blockIdx.x * 256 + threadIdx.x;
  if (g < 8192) {
    int r = g & 15, gq = (g >> 4) & 3, mtg = (g >> 6) & 15, ks = g >> 10;
    const float* src = conv_w + (mtg * 16 + r) * 256 + ks * 32 + gq * 8;
    unsigned v0 = f2bf(src[0]) | (f2bf(src[1]) << 16);
    unsigned v1 = f2bf(src[2]) | (f2bf(src[3]) << 16);
    unsigned v2 = f2bf(src[4]) | (f2bf(src[5]) << 16);
    unsigned v3 = f2bf(src[6]) | (f2bf(src[7]) << 16);
    uint4 q; q.x = v0; q.y = v1; q.z = v2; q.w = v3;
    *(uint4*)(wimg + g * 8) = q;
  } else if (g < 9216) {
    int g2 = g - 8192;
    int r = g2 & 15, gq = (g2 >> 4) & 3, mt = (g2 >> 6) & 1, ks2 = g2 >> 7;
    int m2 = mt * 16 + r;
    int o0 = ks2 * 32 + gq * 8;
    unsigned short v[8];
#pragma unroll
    for (int e = 0; e < 8; ++e) {
      float f = 0.f;
      if (m2 < 24) f = pos_w[m2 * 256 + o0 + e];
      else if (m2 == 24) f = patch_w[o0 + e];
      v[e] = (unsigned short)f2bf(f);
    }
    uint4 q;
    q.x = (unsigned)v[0] | ((unsigned)v[1] << 16);
    q.y = (unsigned)v[2] | ((unsigned)v[3] << 16);
    q.z = (unsigned)v[4] | ((unsigned)v[5] << 16);
    q.w = (unsigned)v[6] | ((unsigned)v[7] << 16);
    *(uint4*)(w2img + g2 * 8) = q;
  }
}

// ---------------------------------------------------------------------------
// main fused kernel: 1 block = 1 batch row, 1024 threads (16 waves),
// 2 blocks/CU -> 8 waves/SIMD. Each wave owns 16 o's (acc = 24 regs).
// K-loop: 4 supersteps (2 K-steps each), ONE barrier per superstep.
// bfimg chunks XOR-swizzled (chunk ^= (kr>>1)&3) to break the 8-way bank
// conflict on the MFMA b-frag ds_read_b128 (lanes 0-15 previously hit only
// bank groups {0,16}; now spread across all 8 groups -> 2-way = free).
// ---------------------------------------------------------------------------
__global__ __launch_bounds__(1024, 8)
void policy_main(const float* __restrict__ x,
                 const int* __restrict__ am,
                 const unsigned short* __restrict__ wimg,
                 const unsigned short* __restrict__ w2img,
                 const float* __restrict__ bn_gamma, const float* __restrict__ bn_beta,
                 const float* __restrict__ bn_mean, const float* __restrict__ bn_var,
                 const float* __restrict__ type_w, const float* __restrict__ type_b,
                 const float* __restrict__ patch_b,
                 const float* __restrict__ slot_w, const float* __restrict__ slot_b,
                 const float* __restrict__ orient_w, const float* __restrict__ orient_b,
                 const float* __restrict__ pos_b,
                 float* __restrict__ out)
{
  // Time-unioned region (66048 B):
  //   K-loop: f32buf[4] (4x10368 @ 0) + bfimg[4] (4x6144 @ 41472) = 66048
  //   then pT (49152 bf16), then s_out2 (13312 f32).
  __shared__ __align__(16) char s_big[66048];
  __shared__ __align__(16) float s_scale[256];
  __shared__ __align__(16) float s_bias[256];
  __shared__ __align__(16) float s_pmean[256];
  __shared__ float s_part[240];
  __shared__ float s_hl[30];
  __shared__ int s_omask[24];
  __shared__ int s_misc[6];

  char* f32buf = s_big;                    // [4][10368 B] raw x tiles
  char* bfimg  = s_big + 41472;            // [4][6144 B]  bf16 B-frag images
  unsigned short* pT = (unsigned short*)s_big;
  float* s_out2 = (float*)s_big;

  const int tid = threadIdx.x;
  const int w  = tid >> 6;     // wave 0..15
  const int l  = tid & 63;
  const int b  = blockIdx.x;
  const float* xb = x + (size_t)b * (256 * 81);

  if (tid < 256) { // BN folded scale/bias
    float sc = bn_gamma[tid] * rsqrtf(bn_var[tid] + 1e-5f);
    s_scale[tid] = sc;
    s_bias[tid]  = bn_beta[tid] - bn_mean[tid] * sc;
  }

  const int kg = l >> 4;   // MFMA k-group 0..3
  const int kr = l & 15;   // MFMA row/col lane 0..15
  const int g4 = kg * 4;
  // Swizzled b-frag chunk offset (see header comment).
  const int fragoff = (((kr * 4 + kg) ^ ((kr >> 1) & 3)) * 16);

  f32x4 acc[6];            // one 16-o M-frag x 6 N-frags = 24 VGPR
#pragma unroll
  for (int j = 0; j < 6; ++j) {
    f32x4 z = {0.f, 0.f, 0.f, 0.f};
    acc[j] = z;
  }

  // x-tile ks: contiguous 10368B (648x16B) chunk -> LDS DMA; 1 DMA per thread
  // for tid<648 (partial-exec waves fine; in-loop waits drain to 0).
  auto STAGE = [&](int ks) {
    const char* g = (const char*)xb + ks * 10368;
    char* lb = f32buf + (ks & 3) * 10368;
    if (tid < 648) GL16(g + tid * 16, lb + tid * 16);
  };

  // One transpose chunk: f32 [c][hw] tile t, chunk q (of 384) -> bf16 B-frag,
  // written at swizzled position q ^ ((q>>3)&3) (same map the reader uses).
  auto TRX = [&](int t, int q) {
    const float* src = (const float*)(f32buf + (t & 3) * 10368);
    char* dst = bfimg + (t & 3) * 6144;
    int nt_ = q >> 6, kr_ = (q >> 2) & 15, kg_ = q & 3;
    const float* s = src + kg_ * 648 + nt_ * 16 + kr_;
    uint4 v;
    v.x = cvtpk(s[0],   s[81]);
    v.y = cvtpk(s[162], s[243]);
    v.z = cvtpk(s[324], s[405]);
    v.w = cvtpk(s[486], s[567]);
    int qs = q ^ ((q >> 3) & 3);
    *(uint4*)(dst + qs * 16) = v;
  };
  // Two tiles (768 chunks) over 1024 threads: 1 chunk each for tid<768.
  auto TRANSPOSE2 = [&](int tA, int tB) {
    if (tid < 384)      TRX(tA, tid);
    else if (tid < 768) TRX(tB, tid - 384);
  };

  // ---- Prologue: stage tiles 0..3; build images 0,1 ------------------------
  STAGE(0); STAGE(1); STAGE(2); STAGE(3);             // <=4 DMA per wave
  asm volatile("s_waitcnt vmcnt(2)" ::: "memory");    // own D0,D1 landed
  __builtin_amdgcn_s_barrier();                       // all waves' D0,D1 landed
  __builtin_amdgcn_sched_barrier(0);
  TRANSPOSE2(0, 1);
  asm volatile("s_waitcnt vmcnt(0)" ::: "memory");    // D2,D3 landed
  asm volatile("s_waitcnt lgkmcnt(0)" ::: "memory");  // images 0,1 visible
  __builtin_amdgcn_s_barrier();
  __builtin_amdgcn_sched_barrier(0);

  // Superstep s (tiles t0=2s, t1=2s+1): stage {t0+4,t1+4} only for s<2
  // (tiles 8,9 don't exist); transpose {t0+2,t1+2} for s<3 (staged+drained
  // one superstep earlier); MFMA sources disjoint from transpose targets.
  auto SUPER = [&](int s) {
    const int t0 = 2 * s, t1 = t0 + 1;
    short8 af0, af1;
    {
      const unsigned short* ab = wimg + w * 512 + kg * 128 + kr * 8;
      af0 = *(const short8*)(ab + t0 * 8192);
      af1 = *(const short8*)(ab + t1 * 8192);
    }
    __builtin_amdgcn_sched_barrier(0);      // pin af before the new DMAs
    if (s < 2) {
      STAGE(t0 + 4);
      STAGE(t1 + 4);
    }
    if (s < 3) TRANSPOSE2(t0 + 2, t1 + 2);
    const char* bi0 = bfimg + (t0 & 3) * 6144;
    const char* bi1 = bfimg + (t1 & 3) * 6144;
    __builtin_amdgcn_s_setprio(1);
#pragma unroll
    for (int nt = 0; nt < 6; ++nt) {
      short8 bf = *(const short8*)(bi0 + nt * 1024 + fragoff);
      acc[nt] = __builtin_amdgcn_mfma_f32_16x16x32_bf16(af0, bf, acc[nt], 0, 0, 0);
    }
#pragma unroll
    for (int nt = 0; nt < 6; ++nt) {
      short8 bf = *(const short8*)(bi1 + nt * 1024 + fragoff);
      acc[nt] = __builtin_amdgcn_mfma_f32_16x16x32_bf16(af1, bf, acc[nt], 0, 0, 0);
    }
    __builtin_amdgcn_s_setprio(0);
    if (s < 3) {
      asm volatile("s_waitcnt vmcnt(0)" ::: "memory");   // new DMAs landed
      asm volatile("s_waitcnt lgkmcnt(0)" ::: "memory"); // new images visible
      __builtin_amdgcn_s_barrier();
      __builtin_amdgcn_sched_barrier(0);
    } else {
      __syncthreads();                      // full fence before pT overlays
    }
  };

  SUPER(0); SUPER(1); SUPER(2); SUPER(3);

  // ---------------- BN+ReLU -> pT (bf16, GEMM-2 B-frag layout) + p_mean -----
  {
    int ob = w * 16 + g4;
    float sc0 = s_scale[ob], sc1 = s_scale[ob + 1], sc2 = s_scale[ob + 2], sc3 = s_scale[ob + 3];
    float bi0 = s_bias[ob],  bi1 = s_bias[ob + 1],  bi2 = s_bias[ob + 2],  bi3 = s_bias[ob + 3];
    float vs0 = 0.f, vs1 = 0.f, vs2 = 0.f, vs3 = 0.f;
    int ks2 = ob >> 5;
    int j2  = (ob >> 3) & 3;
    int e0  = ob & 7;
    char* pbase = (char*)pT + ks2 * 6144 + j2 * 256 + kr * 16 + e0 * 2;
#pragma unroll
    for (int nt = 0; nt < 6; ++nt) {
      float v0 = fmaxf(acc[nt][0] * sc0 + bi0, 0.f);
      float v1 = fmaxf(acc[nt][1] * sc1 + bi1, 0.f);
      float v2 = fmaxf(acc[nt][2] * sc2 + bi2, 0.f);
      float v3 = fmaxf(acc[nt][3] * sc3 + bi3, 0.f);
      if (nt < 5 || kr == 0) { vs0 += v0; vs1 += v1; vs2 += v2; vs3 += v3; } // hw<=80
      uint2 pvv;
      pvv.x = cvtpk(v0, v1);
      pvv.y = cvtpk(v2, v3);
      *(uint2*)(pbase + nt * 1024) = pvv;
    }
    float vv[4] = {vs0, vs1, vs2, vs3};
#pragma unroll
    for (int i = 0; i < 4; ++i) {
      float s = vv[i];
      s += __shfl_xor(s, 1);
      s += __shfl_xor(s, 2);
      s += __shfl_xor(s, 4);
      s += __shfl_xor(s, 8);
      vv[i] = s;
    }
    if (kr == 0) {
      s_pmean[ob]     = vv[0] * (1.f / 81.f);
      s_pmean[ob + 1] = vv[1] * (1.f / 81.f);
      s_pmean[ob + 2] = vv[2] * (1.f / 81.f);
      s_pmean[ob + 3] = vv[3] * (1.f / 81.f);
    }
  }
  __syncthreads();   // pT + s_pmean visible

  // ---------------- Split phase: waves 0-3 GEMM-2 | waves 4-7 masks+heads ---
  const int* amr = am + (size_t)b * ACT;
  const int mt  = w & 1;
  const int ntb = (w >> 1) * 3;
  f32x4 acc2[3];
#pragma unroll
  for (int t = 0; t < 3; ++t) { f32x4 z = {0.f, 0.f, 0.f, 0.f}; acc2[t] = z; }

  if (w < 4) {
    // GEMM-2: out2[m2, hw] = w2 * p
#pragma unroll
    for (int ks2 = 0; ks2 < 8; ++ks2) {
      const unsigned short* ap = w2img + ((ks2 * 2 + mt) * 4 + kg) * 128 + kr * 8;
      short8 a2 = *(const short8*)ap;
#pragma unroll
      for (int t = 0; t < 3; ++t) {
        const short8* bp = (const short8*)((const char*)pT + ks2 * 6144 + (ntb + t) * 1024 + kg * 256 + kr * 16);
        acc2[t] = __builtin_amdgcn_mfma_f32_16x16x32_bf16(a2, *bp, acc2[t], 0, 0, 0);
      }
    }
  } else if (w < 8) {
    // masks
    for (int t = w - 4; t < 25; t += 4) {
      int off = (t < 24) ? (82 + t * 81) : 1;
      int v1 = amr[off + l];
      int v2 = (l < 17) ? amr[off + 64 + l] : 0;
      unsigned long long bal = __ballot((v1 | v2) != 0);
      if (l == 0) {
        int any = (bal != 0ULL) ? 1 : 0;
        if (t < 24) s_omask[t] = any; else s_misc[0] = any;
      }
    }
    // head partial dots (30 heads x 8 segments = 240 units on waves 4-7)
    int hh = tid - 256;
    if (hh < 240) {
      int h = hh >> 3, seg = hh & 7;
      const float* wp = (h < 3) ? (type_w + h * 256)
                      : (h < 6) ? (slot_w + (h - 3) * 256)
                                : (orient_w + (h - 6) * 256);
      float p = 0.f;
      int base = seg * 32;
#pragma unroll 8
      for (int e = 0; e < 32; ++e) p += s_pmean[base + e] * wp[base + e];
      s_part[hh] = p;
    }
  }
  __syncthreads();   // pT reads done; s_part/s_omask/s_misc visible

  // -------- P4: s_out2 (overlays pT) + head combine + slot/buy any-masks ----
  if (w < 4) {
#pragma unroll
    for (int t = 0; t < 3; ++t) {
      int hw = (ntb + t) * 16 + kr;
      int m2 = mt * 16 + g4;
#pragma unroll
      for (int i = 0; i < 4; ++i)
        s_out2[(m2 + i) * 104 + hw] = acc2[t][i];
    }
  }
  if (tid < 30) {
    float a = 0.f;
#pragma unroll
    for (int e = 0; e < 8; ++e) a += s_part[tid * 8 + e];
    a += (tid < 3) ? type_b[tid] : (tid < 6) ? slot_b[tid - 3] : orient_b[tid - 6];
    s_hl[tid] = a;
  }
  if (tid == 32) {
    int sa0 = 0, sa1 = 0, sa2 = 0;
#pragma unroll
    for (int rr = 0; rr < 8; ++rr) { sa0 |= s_omask[rr]; sa1 |= s_omask[8 + rr]; sa2 |= s_omask[16 + rr]; }
    s_misc[1] = sa0; s_misc[2] = sa1; s_misc[3] = sa2;
    s_misc[4] = sa0 | sa1 | sa2;
  }
  __syncthreads();

  // -------- P6: per-thread small softmaxes (broadcast LDS reads) + 81-wide --
  float tlp0, tlp1, tlp2;
  {
    int mk0 = amr[0] > 0, mk1 = s_misc[0], mk2 = s_misc[4];
    float g0 = mk0 ? s_hl[0] : NEGV;
    float g1 = mk1 ? s_hl[1] : NEGV;
    float g2 = mk2 ? s_hl[2] : NEGV;
    float m = fmaxf(fmaxf(g0, g1), g2);
    float ls = m + __logf(__expf(g0 - m) + __expf(g1 - m) + __expf(g2 - m));
    tlp0 = fmaxf(g0 - ls, -100.f);
    tlp1 = fmaxf(g1 - ls, -100.f);
    tlp2 = fmaxf(g2 - ls, -100.f);
  }
  float slp[3];
  {
    float g[3]; float m = -3.0e38f;
#pragma unroll
    for (int s = 0; s < 3; ++s) { g[s] = s_misc[1 + s] ? s_hl[3 + s] : NEGV; m = fmaxf(m, g[s]); }
    float sum = 0.f;
#pragma unroll
    for (int s = 0; s < 3; ++s) sum += __expf(g[s] - m);
    float ls = m + __logf(sum);
#pragma unroll
    for (int s = 0; s < 3; ++s) slp[s] = fmaxf(g[s] - ls, -100.f);
  }

  float* ob_out = out + (size_t)b * ACT;
  for (int t = w; t < 25; t += 16) {
    int off = (t < 24) ? (82 + t * 81) : 1;
    float badd = (t < 24) ? pos_b[t] : patch_b[0];
    int a1 = amr[off + l];
    int a2v = (l < 17) ? amr[off + 64 + l] : 0;
    float lg1 = (a1 > 0) ? (s_out2[t * 104 + l] + badd) : NEGV;
    float lg2 = (l < 17 && a2v > 0) ? (s_out2[t * 104 + 64 + l] + badd) : NEGV;
    float mx = fmaxf(lg1, (l < 17) ? lg2 : -3.0e38f);
#pragma unroll
    for (int mm = 1; mm < 64; mm <<= 1) mx = fmaxf(mx, __shfl_xor(mx, mm));
    float sm = __expf(lg1 - mx) + ((l < 17) ? __expf(lg2 - mx) : 0.f);
#pragma unroll
    for (int mm = 1; mm < 64; mm <<= 1) sm += __shfl_xor(sm, mm);
    float lse = mx + __logf(sm);
    float lp1 = fmaxf(lg1 - lse, -100.f);
    float lp2 = fmaxf(lg2 - lse, -100.f);
    float addj; int obase;
    if (t < 24) {
      int sl = t >> 3;
      float g[8]; float m = -3.0e38f;
#pragma unroll
      for (int rr = 0; rr < 8; ++rr) {
        g[rr] = s_omask[sl * 8 + rr] ? s_hl[6 + sl * 8 + rr] : NEGV;
        m = fmaxf(m, g[rr]);
      }
      float sum = 0.f;
#pragma unroll
      for (int rr = 0; rr < 8; ++rr) sum += __expf(g[rr] - m);
      float ls = m + __logf(sum);
      float olp_t = fmaxf(g[t & 7] - ls, -100.f);
      addj = tlp2 + slp[sl] + olp_t;
      obase = 82 + t * 81;
    } else {
      addj = tlp1;
      obase = 1;
    }
    ob_out[obase + l] = addj + lp1;
    if (l < 17) ob_out[obase + 64 + l] = addj + lp2;
    if (t == 24 && l == 0) ob_out[0] = tlp0;
  }
}

// ---------------------------------------------------------------------------
extern "C" void kernel_launch(void* const* d_in, const int* in_sizes, int n_in,
                              void* d_out, int out_size, void* d_ws, size_t ws_size,
                              hipStream_t stream) {
  (void)in_sizes; (void)n_in; (void)out_size; (void)ws_size;
  const float* x        = (const float*)d_in[0];
  const int*   amask    = (const int*)d_in[1];
  const float* conv_w   = (const float*)d_in[2];
  const float* bn_gamma = (const float*)d_in[3];
  const float* bn_beta  = (const float*)d_in[4];
  const float* bn_mean  = (const float*)d_in[5];
  const float* bn_var   = (const float*)d_in[6];
  const float* type_w   = (const float*)d_in[7];
  const float* type_b   = (const float*)d_in[8];
  const float* patch_w  = (const float*)d_in[9];
  const float* patch_b  = (const float*)d_in[10];
  const float* slot_w   = (const float*)d_in[11];
  const float* slot_b   = (const float*)d_in[12];
  const float* orient_w = (const float*)d_in[13];
  const float* orient_b = (const float*)d_in[14];
  const float* pos_w    = (const float*)d_in[15];
  const float* pos_b    = (const float*)d_in[16];
  float* outp = (float*)d_out;

  unsigned short* wimg  = (unsigned short*)d_ws;         // 131072 B
  unsigned short* w2img = wimg + 65536;                  // 16384 B

  prep_w_kernel<<<36, 256, 0, stream>>>(conv_w, pos_w, patch_w, wimg, w2img);
  policy_main<<<4096, 1024, 0, stream>>>(x, amask, wimg, w2img,
                                         bn_gamma, bn_beta, bn_mean, bn_var,
                                         type_w, type_b, patch_b,
                                         slot_w, slot_b, orient_w, orient_b,
                                         pos_b, outp);
}

// Round 15
// 175.951 us; speedup vs baseline: 2.4515x; 1.0385x over previous
//
#include <hip/hip_runtime.h>

#define ACT 2026
#define NEGV -1.0e9f

typedef short short8 __attribute__((ext_vector_type(8)));
typedef float f32x4 __attribute__((ext_vector_type(4)));

__device__ __forceinline__ unsigned f2bf(float f) {
  unsigned u = __float_as_uint(f);
  return (u + 0x7FFFu + ((u >> 16) & 1u)) >> 16;   // RNE f32->bf16
}

__device__ __forceinline__ unsigned cvtpk(float lo, float hi) {
  unsigned r;
  asm("v_cvt_pk_bf16_f32 %0, %1, %2" : "=v"(r) : "v"(lo), "v"(hi));
  return r;
}

#define GL16(gp, lp) __builtin_amdgcn_global_load_lds(                         \
    (const __attribute__((address_space(1))) void*)(gp),                       \
    (__attribute__((address_space(3))) void*)(lp), 16, 0, 0)

// ---------------------------------------------------------------------------
// prep kernel: fragment-major bf16 images of conv_w and the 25-row head panel
// ---------------------------------------------------------------------------
__global__ void prep_w_kernel(const float* __restrict__ conv_w,
                              const float* __restrict__ pos_w,
                              const float* __restrict__ patch_w,
                              unsigned short* __restrict__ wimg,
                              unsigned short* __restrict__ w2img) {
  int g = blockIdx.x * 256 + threadIdx.x;
  if (g < 8192) {
    int r = g & 15, gq = (g >> 4) & 3, mtg = (g >> 6) & 15, ks = g >> 10;
    const float* src = conv_w + (mtg * 16 + r) * 256 + ks * 32 + gq * 8;
    unsigned v0 = f2bf(src[0]) | (f2bf(src[1]) << 16);
    unsigned v1 = f2bf(src[2]) | (f2bf(src[3]) << 16);
    unsigned v2 = f2bf(src[4]) | (f2bf(src[5]) << 16);
    unsigned v3 = f2bf(src[6]) | (f2bf(src[7]) << 16);
    uint4 q; q.x = v0; q.y = v1; q.z = v2; q.w = v3;
    *(uint4*)(wimg + g * 8) = q;
  } else if (g < 9216) {
    int g2 = g - 8192;
    int r = g2 & 15, gq = (g2 >> 4) & 3, mt = (g2 >> 6) & 1, ks2 = g2 >> 7;
    int m2 = mt * 16 + r;
    int o0 = ks2 * 32 + gq * 8;
    unsigned short v[8];
#pragma unroll
    for (int e = 0; e < 8; ++e) {
      float f = 0.f;
      if (m2 < 24) f = pos_w[m2 * 256 + o0 + e];
      else if (m2 == 24) f = patch_w[o0 + e];
      v[e] = (unsigned short)f2bf(f);
    }
    uint4 q;
    q.x = (unsigned)v[0] | ((unsigned)v[1] << 16);
    q.y = (unsigned)v[2] | ((unsigned)v[3] << 16);
    q.z = (unsigned)v[4] | ((unsigned)v[5] << 16);
    q.w = (unsigned)v[6] | ((unsigned)v[7] << 16);
    *(uint4*)(w2img + g2 * 8) = q;
  }
}

// ---------------------------------------------------------------------------
// main fused kernel: 1 block = 1 batch row, 1024 threads (16 waves),
// 2 blocks/CU -> 8 waves/SIMD. Each wave owns 16 o's (acc = 24 regs).
// K-loop: 4 supersteps (2 K-steps each), ONE barrier per superstep.
// bfimg chunks XOR-swizzled (chunk ^= (kr>>1)&3) to break the 8-way bank
// conflict on the MFMA b-frag ds_read_b128.
// Tail: GEMM-2 on 12 waves (1 nt each) | masks+heads on waves 12-15 with
// amr loads issued ahead of the head dots (latency overlap).
// ---------------------------------------------------------------------------
__global__ __launch_bounds__(1024, 8)
void policy_main(const float* __restrict__ x,
                 const int* __restrict__ am,
                 const unsigned short* __restrict__ wimg,
                 const unsigned short* __restrict__ w2img,
                 const float* __restrict__ bn_gamma, const float* __restrict__ bn_beta,
                 const float* __restrict__ bn_mean, const float* __restrict__ bn_var,
                 const float* __restrict__ type_w, const float* __restrict__ type_b,
                 const float* __restrict__ patch_b,
                 const float* __restrict__ slot_w, const float* __restrict__ slot_b,
                 const float* __restrict__ orient_w, const float* __restrict__ orient_b,
                 const float* __restrict__ pos_b,
                 float* __restrict__ out)
{
  // Time-unioned region (66048 B):
  //   K-loop: f32buf[4] (4x10368 @ 0) + bfimg[4] (4x6144 @ 41472) = 66048
  //   then pT (49152 bf16), then s_out2 (13312 f32).
  __shared__ __align__(16) char s_big[66048];
  __shared__ __align__(16) float s_scale[256];
  __shared__ __align__(16) float s_bias[256];
  __shared__ __align__(16) float s_pmean[256];
  __shared__ float s_part[240];
  __shared__ float s_hl[30];
  __shared__ int s_omask[24];
  __shared__ int s_misc[6];

  char* f32buf = s_big;                    // [4][10368 B] raw x tiles
  char* bfimg  = s_big + 41472;            // [4][6144 B]  bf16 B-frag images
  unsigned short* pT = (unsigned short*)s_big;
  float* s_out2 = (float*)s_big;

  const int tid = threadIdx.x;
  const int w  = tid >> 6;     // wave 0..15
  const int l  = tid & 63;
  const int b  = blockIdx.x;
  const float* xb = x + (size_t)b * (256 * 81);

  if (tid < 256) { // BN folded scale/bias
    float sc = bn_gamma[tid] * rsqrtf(bn_var[tid] + 1e-5f);
    s_scale[tid] = sc;
    s_bias[tid]  = bn_beta[tid] - bn_mean[tid] * sc;
  }

  const int kg = l >> 4;   // MFMA k-group 0..3
  const int kr = l & 15;   // MFMA row/col lane 0..15
  const int g4 = kg * 4;
  // Swizzled b-frag chunk offset.
  const int fragoff = (((kr * 4 + kg) ^ ((kr >> 1) & 3)) * 16);

  f32x4 acc[6];            // one 16-o M-frag x 6 N-frags = 24 VGPR
#pragma unroll
  for (int j = 0; j < 6; ++j) {
    f32x4 z = {0.f, 0.f, 0.f, 0.f};
    acc[j] = z;
  }

  // x-tile ks: contiguous 10368B (648x16B) chunk -> LDS DMA; 1 DMA per thread
  // for tid<648 (partial-exec waves fine; in-loop waits drain to 0).
  auto STAGE = [&](int ks) {
    const char* g = (const char*)xb + ks * 10368;
    char* lb = f32buf + (ks & 3) * 10368;
    if (tid < 648) GL16(g + tid * 16, lb + tid * 16);
  };

  // One transpose chunk: f32 [c][hw] tile t, chunk q (of 384) -> bf16 B-frag,
  // written at swizzled position q ^ ((q>>3)&3) (same map the reader uses).
  auto TRX = [&](int t, int q) {
    const float* src = (const float*)(f32buf + (t & 3) * 10368);
    char* dst = bfimg + (t & 3) * 6144;
    int nt_ = q >> 6, kr_ = (q >> 2) & 15, kg_ = q & 3;
    const float* s = src + kg_ * 648 + nt_ * 16 + kr_;
    uint4 v;
    v.x = cvtpk(s[0],   s[81]);
    v.y = cvtpk(s[162], s[243]);
    v.z = cvtpk(s[324], s[405]);
    v.w = cvtpk(s[486], s[567]);
    int qs = q ^ ((q >> 3) & 3);
    *(uint4*)(dst + qs * 16) = v;
  };
  // Two tiles (768 chunks) over 1024 threads: 1 chunk each for tid<768.
  auto TRANSPOSE2 = [&](int tA, int tB) {
    if (tid < 384)      TRX(tA, tid);
    else if (tid < 768) TRX(tB, tid - 384);
  };

  // ---- Prologue: stage tiles 0..3; build images 0,1 ------------------------
  STAGE(0); STAGE(1); STAGE(2); STAGE(3);             // <=4 DMA per wave
  asm volatile("s_waitcnt vmcnt(2)" ::: "memory");    // own D0,D1 landed
  __builtin_amdgcn_s_barrier();                       // all waves' D0,D1 landed
  __builtin_amdgcn_sched_barrier(0);
  TRANSPOSE2(0, 1);
  asm volatile("s_waitcnt vmcnt(0)" ::: "memory");    // D2,D3 landed
  asm volatile("s_waitcnt lgkmcnt(0)" ::: "memory");  // images 0,1 visible
  __builtin_amdgcn_s_barrier();
  __builtin_amdgcn_sched_barrier(0);

  // Superstep s (tiles t0=2s, t1=2s+1): stage {t0+4,t1+4} only for s<2
  // (tiles 8,9 don't exist); transpose {t0+2,t1+2} for s<3 (staged+drained
  // one superstep earlier); MFMA sources disjoint from transpose targets.
  auto SUPER = [&](int s) {
    const int t0 = 2 * s, t1 = t0 + 1;
    short8 af0, af1;
    {
      const unsigned short* ab = wimg + w * 512 + kg * 128 + kr * 8;
      af0 = *(const short8*)(ab + t0 * 8192);
      af1 = *(const short8*)(ab + t1 * 8192);
    }
    __builtin_amdgcn_sched_barrier(0);      // pin af before the new DMAs
    if (s < 2) {
      STAGE(t0 + 4);
      STAGE(t1 + 4);
    }
    if (s < 3) TRANSPOSE2(t0 + 2, t1 + 2);
    const char* bi0 = bfimg + (t0 & 3) * 6144;
    const char* bi1 = bfimg + (t1 & 3) * 6144;
    __builtin_amdgcn_s_setprio(1);
#pragma unroll
    for (int nt = 0; nt < 6; ++nt) {
      short8 bf = *(const short8*)(bi0 + nt * 1024 + fragoff);
      acc[nt] = __builtin_amdgcn_mfma_f32_16x16x32_bf16(af0, bf, acc[nt], 0, 0, 0);
    }
#pragma unroll
    for (int nt = 0; nt < 6; ++nt) {
      short8 bf = *(const short8*)(bi1 + nt * 1024 + fragoff);
      acc[nt] = __builtin_amdgcn_mfma_f32_16x16x32_bf16(af1, bf, acc[nt], 0, 0, 0);
    }
    __builtin_amdgcn_s_setprio(0);
    if (s < 3) {
      asm volatile("s_waitcnt vmcnt(0)" ::: "memory");   // new DMAs landed
      asm volatile("s_waitcnt lgkmcnt(0)" ::: "memory"); // new images visible
      __builtin_amdgcn_s_barrier();
      __builtin_amdgcn_sched_barrier(0);
    } else {
      __syncthreads();                      // full fence before pT overlays
    }
  };

  SUPER(0); SUPER(1); SUPER(2); SUPER(3);

  // ---------------- BN+ReLU -> pT (bf16, GEMM-2 B-frag layout) + p_mean -----
  {
    int ob = w * 16 + g4;
    float sc0 = s_scale[ob], sc1 = s_scale[ob + 1], sc2 = s_scale[ob + 2], sc3 = s_scale[ob + 3];
    float bi0 = s_bias[ob],  bi1 = s_bias[ob + 1],  bi2 = s_bias[ob + 2],  bi3 = s_bias[ob + 3];
    float vs0 = 0.f, vs1 = 0.f, vs2 = 0.f, vs3 = 0.f;
    int ks2 = ob >> 5;
    int j2  = (ob >> 3) & 3;
    int e0  = ob & 7;
    char* pbase = (char*)pT + ks2 * 6144 + j2 * 256 + kr * 16 + e0 * 2;
#pragma unroll
    for (int nt = 0; nt < 6; ++nt) {
      float v0 = fmaxf(acc[nt][0] * sc0 + bi0, 0.f);
      float v1 = fmaxf(acc[nt][1] * sc1 + bi1, 0.f);
      float v2 = fmaxf(acc[nt][2] * sc2 + bi2, 0.f);
      float v3 = fmaxf(acc[nt][3] * sc3 + bi3, 0.f);
      if (nt < 5 || kr == 0) { vs0 += v0; vs1 += v1; vs2 += v2; vs3 += v3; } // hw<=80
      uint2 pvv;
      pvv.x = cvtpk(v0, v1);
      pvv.y = cvtpk(v2, v3);
      *(uint2*)(pbase + nt * 1024) = pvv;
    }
    float vv[4] = {vs0, vs1, vs2, vs3};
#pragma unroll
    for (int i = 0; i < 4; ++i) {
      float s = vv[i];
      s += __shfl_xor(s, 1);
      s += __shfl_xor(s, 2);
      s += __shfl_xor(s, 4);
      s += __shfl_xor(s, 8);
      vv[i] = s;
    }
    if (kr == 0) {
      s_pmean[ob]     = vv[0] * (1.f / 81.f);
      s_pmean[ob + 1] = vv[1] * (1.f / 81.f);
      s_pmean[ob + 2] = vv[2] * (1.f / 81.f);
      s_pmean[ob + 3] = vv[3] * (1.f / 81.f);
    }
  }
  __syncthreads();   // pT + s_pmean visible

  // ---------------- Split phase: waves 0-11 GEMM-2 | waves 12-15 masks+heads
  const int* amr = am + (size_t)b * ACT;
  const int mt12 = w & 1;        // for w<12
  const int nt12 = w >> 1;       // 0..5
  f32x4 acc2 = {0.f, 0.f, 0.f, 0.f};

  if (w < 12) {
    // GEMM-2: one (mt,nt) pair per wave; 8 MFMA + 8 b128 LDS reads
#pragma unroll
    for (int ks2 = 0; ks2 < 8; ++ks2) {
      const unsigned short* ap = w2img + ((ks2 * 2 + mt12) * 4 + kg) * 128 + kr * 8;
      short8 a2 = *(const short8*)ap;
      const short8* bp = (const short8*)((const char*)pT + ks2 * 6144 + nt12 * 1024 + kg * 256 + kr * 16);
      acc2 = __builtin_amdgcn_mfma_f32_16x16x32_bf16(a2, *bp, acc2, 0, 0, 0);
    }
  } else {
    // waves 12-15: issue amr loads first, head dots while in flight, then
    // ballots (use forces the wait).
    const int t0 = w - 12;               // 0..3
    int va[7], vb[7];
#pragma unroll
    for (int i = 0; i < 7; ++i) {
      int t = t0 + 4 * i;
      va[i] = 0; vb[i] = 0;
      if (t < 25) {
        int off = (t < 24) ? (82 + t * 81) : 1;
        va[i] = amr[off + l];
        vb[i] = (l < 17) ? amr[off + 64 + l] : 0;
      }
    }
    // head partial dots (30 heads x 8 segments = 240 units on waves 12-15)
    int hh = tid - 768;
    if (hh < 240) {
      int h = hh >> 3, seg = hh & 7;
      const float* wp = (h < 3) ? (type_w + h * 256)
                      : (h < 6) ? (slot_w + (h - 3) * 256)
                                : (orient_w + (h - 6) * 256);
      float p = 0.f;
      int base = seg * 32;
#pragma unroll 8
      for (int e = 0; e < 32; ++e) p += s_pmean[base + e] * wp[base + e];
      s_part[hh] = p;
    }
    // ballots
#pragma unroll
    for (int i = 0; i < 7; ++i) {
      int t = t0 + 4 * i;
      if (t < 25) {
        unsigned long long bal = __ballot((va[i] | vb[i]) != 0);
        if (l == 0) {
          int any = (bal != 0ULL) ? 1 : 0;
          if (t < 24) s_omask[t] = any; else s_misc[0] = any;
        }
      }
    }
  }
  __syncthreads();   // pT reads done; s_part/s_omask/s_misc visible

  // -------- P4: s_out2 (overlays pT) + head combine + slot/buy any-masks ----
  if (w < 12) {
    int hw = nt12 * 16 + kr;
    int m2 = mt12 * 16 + g4;
#pragma unroll
    for (int i = 0; i < 4; ++i)
      s_out2[(m2 + i) * 104 + hw] = acc2[i];
  }
  if (tid < 30) {
    float a = 0.f;
#pragma unroll
    for (int e = 0; e < 8; ++e) a += s_part[tid * 8 + e];
    a += (tid < 3) ? type_b[tid] : (tid < 6) ? slot_b[tid - 3] : orient_b[tid - 6];
    s_hl[tid] = a;
  }
  if (tid == 32) {
    int sa0 = 0, sa1 = 0, sa2 = 0;
#pragma unroll
    for (int rr = 0; rr < 8; ++rr) { sa0 |= s_omask[rr]; sa1 |= s_omask[8 + rr]; sa2 |= s_omask[16 + rr]; }
    s_misc[1] = sa0; s_misc[2] = sa1; s_misc[3] = sa2;
    s_misc[4] = sa0 | sa1 | sa2;
  }
  __syncthreads();

  // -------- P6: per-thread small softmaxes (broadcast LDS reads) + 81-wide --
  float tlp0, tlp1, tlp2;
  {
    int mk0 = amr[0] > 0, mk1 = s_misc[0], mk2 = s_misc[4];
    float g0 = mk0 ? s_hl[0] : NEGV;
    float g1 = mk1 ? s_hl[1] : NEGV;
    float g2 = mk2 ? s_hl[2] : NEGV;
    float m = fmaxf(fmaxf(g0, g1), g2);
    float ls = m + __logf(__expf(g0 - m) + __expf(g1 - m) + __expf(g2 - m));
    tlp0 = fmaxf(g0 - ls, -100.f);
    tlp1 = fmaxf(g1 - ls, -100.f);
    tlp2 = fmaxf(g2 - ls, -100.f);
  }
  float slp[3];
  {
    float g[3]; float m = -3.0e38f;
#pragma unroll
    for (int s = 0; s < 3; ++s) { g[s] = s_misc[1 + s] ? s_hl[3 + s] : NEGV; m = fmaxf(m, g[s]); }
    float sum = 0.f;
#pragma unroll
    for (int s = 0; s < 3; ++s) sum += __expf(g[s] - m);
    float ls = m + __logf(sum);
#pragma unroll
    for (int s = 0; s < 3; ++s) slp[s] = fmaxf(g[s] - ls, -100.f);
  }

  float* ob_out = out + (size_t)b * ACT;
  for (int t = w; t < 25; t += 16) {
    int off = (t < 24) ? (82 + t * 81) : 1;
    float badd = (t < 24) ? pos_b[t] : patch_b[0];
    int a1 = amr[off + l];
    int a2v = (l < 17) ? amr[off + 64 + l] : 0;
    float lg1 = (a1 > 0) ? (s_out2[t * 104 + l] + badd) : NEGV;
    float lg2 = (l < 17 && a2v > 0) ? (s_out2[t * 104 + 64 + l] + badd) : NEGV;
    float mx = fmaxf(lg1, (l < 17) ? lg2 : -3.0e38f);
#pragma unroll
    for (int mm = 1; mm < 64; mm <<= 1) mx = fmaxf(mx, __shfl_xor(mx, mm));
    float sm = __expf(lg1 - mx) + ((l < 17) ? __expf(lg2 - mx) : 0.f);
#pragma unroll
    for (int mm = 1; mm < 64; mm <<= 1) sm += __shfl_xor(sm, mm);
    float lse = mx + __logf(sm);
    float lp1 = fmaxf(lg1 - lse, -100.f);
    float lp2 = fmaxf(lg2 - lse, -100.f);
    float addj; int obase;
    if (t < 24) {
      int sl = t >> 3;
      float g[8]; float m = -3.0e38f;
#pragma unroll
      for (int rr = 0; rr < 8; ++rr) {
        g[rr] = s_omask[sl * 8 + rr] ? s_hl[6 + sl * 8 + rr] : NEGV;
        m = fmaxf(m, g[rr]);
      }
      float sum = 0.f;
#pragma unroll
      for (int rr = 0; rr < 8; ++rr) sum += __expf(g[rr] - m);
      float ls = m + __logf(sum);
      float olp_t = fmaxf(g[t & 7] - ls, -100.f);
      addj = tlp2 + slp[sl] + olp_t;
      obase = 82 + t * 81;
    } else {
      addj = tlp1;
      obase = 1;
    }
    ob_out[obase + l] = addj + lp1;
    if (l < 17) ob_out[obase + 64 + l] = addj + lp2;
    if (t == 24 && l == 0) ob_out[0] = tlp0;
  }
}

// ---------------------------------------------------------------------------
extern "C" void kernel_launch(void* const* d_in, const int* in_sizes, int n_in,
                              void* d_out, int out_size, void* d_ws, size_t ws_size,
                              hipStream_t stream) {
  (void)in_sizes; (void)n_in; (void)out_size; (void)ws_size;
  const float* x        = (const float*)d_in[0];
  const int*   amask    = (const int*)d_in[1];
  const float* conv_w   = (const float*)d_in[2];
  const float* bn_gamma = (const float*)d_in[3];
  const float* bn_beta  = (const float*)d_in[4];
  const float* bn_mean  = (const float*)d_in[5];
  const float* bn_var   = (const float*)d_in[6];
  const float* type_w   = (const float*)d_in[7];
  const float* type_b   = (const float*)d_in[8];
  const float* patch_w  = (const float*)d_in[9];
  const float* patch_b  = (const float*)d_in[10];
  const float* slot_w   = (const float*)d_in[11];
  const float* slot_b   = (const float*)d_in[12];
  const float* orient_w = (const float*)d_in[13];
  const float* orient_b = (const float*)d_in[14];
  const float* pos_w    = (const float*)d_in[15];
  const float* pos_b    = (const float*)d_in[16];
  float* outp = (float*)d_out;

  unsigned short* wimg  = (unsigned short*)d_ws;         // 131072 B
  unsigned short* w2img = wimg + 65536;                  // 16384 B

  prep_w_kernel<<<36, 256, 0, stream>>>(conv_w, pos_w, patch_w, wimg, w2img);
  policy_main<<<4096, 1024, 0, stream>>>(x, amask, wimg, w2img,
                                         bn_gamma, bn_beta, bn_mean, bn_var,
                                         type_w, type_b, patch_b,
                                         slot_w, slot_b, orient_w, orient_b,
                                         pos_b, outp);
}

// Round 16
// 172.966 us; speedup vs baseline: 2.4938x; 1.0173x over previous
//
#include <hip/hip_runtime.h>

#define ACT 2026
#define NEGV -1.0e9f

typedef short short8 __attribute__((ext_vector_type(8)));
typedef float f32x4 __attribute__((ext_vector_type(4)));

__device__ __forceinline__ unsigned f2bf(float f) {
  unsigned u = __float_as_uint(f);
  return (u + 0x7FFFu + ((u >> 16) & 1u)) >> 16;   // RNE f32->bf16
}

__device__ __forceinline__ unsigned cvtpk(float lo, float hi) {
  unsigned r;
  asm("v_cvt_pk_bf16_f32 %0, %1, %2" : "=v"(r) : "v"(lo), "v"(hi));
  return r;
}

#define GL16(gp, lp) __builtin_amdgcn_global_load_lds(                         \
    (const __attribute__((address_space(1))) void*)(gp),                       \
    (__attribute__((address_space(3))) void*)(lp), 16, 0, 0)

// ---------------------------------------------------------------------------
// prep kernel: fragment-major bf16 images of conv_w and the 25-row head panel
// ---------------------------------------------------------------------------
__global__ void prep_w_kernel(const float* __restrict__ conv_w,
                              const float* __restrict__ pos_w,
                              const float* __restrict__ patch_w,
                              unsigned short* __restrict__ wimg,
                              unsigned short* __restrict__ w2img) {
  int g = blockIdx.x * 256 + threadIdx.x;
  if (g < 8192) {
    int r = g & 15, gq = (g >> 4) & 3, mtg = (g >> 6) & 15, ks = g >> 10;
    const float* src = conv_w + (mtg * 16 + r) * 256 + ks * 32 + gq * 8;
    unsigned v0 = f2bf(src[0]) | (f2bf(src[1]) << 16);
    unsigned v1 = f2bf(src[2]) | (f2bf(src[3]) << 16);
    unsigned v2 = f2bf(src[4]) | (f2bf(src[5]) << 16);
    unsigned v3 = f2bf(src[6]) | (f2bf(src[7]) << 16);
    uint4 q; q.x = v0; q.y = v1; q.z = v2; q.w = v3;
    *(uint4*)(wimg + g * 8) = q;
  } else if (g < 9216) {
    int g2 = g - 8192;
    int r = g2 & 15, gq = (g2 >> 4) & 3, mt = (g2 >> 6) & 1, ks2 = g2 >> 7;
    int m2 = mt * 16 + r;
    int o0 = ks2 * 32 + gq * 8;
    unsigned short v[8];
#pragma unroll
    for (int e = 0; e < 8; ++e) {
      float f = 0.f;
      if (m2 < 24) f = pos_w[m2 * 256 + o0 + e];
      else if (m2 == 24) f = patch_w[o0 + e];
      v[e] = (unsigned short)f2bf(f);
    }
    uint4 q;
    q.x = (unsigned)v[0] | ((unsigned)v[1] << 16);
    q.y = (unsigned)v[2] | ((unsigned)v[3] << 16);
    q.z = (unsigned)v[4] | ((unsigned)v[5] << 16);
    q.w = (unsigned)v[6] | ((unsigned)v[7] << 16);
    *(uint4*)(w2img + g2 * 8) = q;
  }
}

// ---------------------------------------------------------------------------
// main fused kernel: 1 block = 1 batch row, 1024 threads (16 waves),
// 2 blocks/CU -> 8 waves/SIMD. Each wave owns 16 o's (acc = 24 regs).
// K-loop: 4 supersteps (2 K-steps each), ONE barrier per superstep, and
// NO vmcnt(0) in the loop: superstep order is af -> STAGE -> MFMA (compiler
// af-wait = vmcnt(2) retires stage(s-1)) -> vmcnt(2) (no-op, orders TRX) ->
// TRX -> lgkmcnt(0) -> barrier. stage(s) DMAs stay in flight across the
// barrier and get a full superstep of latency cover (T4 counted-vmcnt).
// bfimg chunks XOR-swizzled (chunk ^= (kr>>1)&3) to break the b128 bank
// conflict. Tail: GEMM-2 on 12 waves | masks+heads on waves 12-15.
// ---------------------------------------------------------------------------
__global__ __launch_bounds__(1024, 8)
void policy_main(const float* __restrict__ x,
                 const int* __restrict__ am,
                 const unsigned short* __restrict__ wimg,
                 const unsigned short* __restrict__ w2img,
                 const float* __restrict__ bn_gamma, const float* __restrict__ bn_beta,
                 const float* __restrict__ bn_mean, const float* __restrict__ bn_var,
                 const float* __restrict__ type_w, const float* __restrict__ type_b,
                 const float* __restrict__ patch_b,
                 const float* __restrict__ slot_w, const float* __restrict__ slot_b,
                 const float* __restrict__ orient_w, const float* __restrict__ orient_b,
                 const float* __restrict__ pos_b,
                 float* __restrict__ out)
{
  // Time-unioned region (66048 B):
  //   K-loop: f32buf[4] (4x10368 @ 0) + bfimg[4] (4x6144 @ 41472) = 66048
  //   then pT (49152 bf16), then s_out2 (13312 f32).
  __shared__ __align__(16) char s_big[66048];
  __shared__ __align__(16) float s_scale[256];
  __shared__ __align__(16) float s_bias[256];
  __shared__ __align__(16) float s_pmean[256];
  __shared__ float s_part[240];
  __shared__ float s_hl[30];
  __shared__ int s_omask[24];
  __shared__ int s_misc[6];

  char* f32buf = s_big;                    // [4][10368 B] raw x tiles
  char* bfimg  = s_big + 41472;            // [4][6144 B]  bf16 B-frag images
  unsigned short* pT = (unsigned short*)s_big;
  float* s_out2 = (float*)s_big;

  const int tid = threadIdx.x;
  const int w  = tid >> 6;     // wave 0..15
  const int l  = tid & 63;
  const int b  = blockIdx.x;
  const float* xb = x + (size_t)b * (256 * 81);

  if (tid < 256) { // BN folded scale/bias
    float sc = bn_gamma[tid] * rsqrtf(bn_var[tid] + 1e-5f);
    s_scale[tid] = sc;
    s_bias[tid]  = bn_beta[tid] - bn_mean[tid] * sc;
  }

  const int kg = l >> 4;   // MFMA k-group 0..3
  const int kr = l & 15;   // MFMA row/col lane 0..15
  const int g4 = kg * 4;
  // Swizzled b-frag chunk offset.
  const int fragoff = (((kr * 4 + kg) ^ ((kr >> 1) & 3)) * 16);

  f32x4 acc[6];            // one 16-o M-frag x 6 N-frags = 24 VGPR
#pragma unroll
  for (int j = 0; j < 6; ++j) {
    f32x4 z = {0.f, 0.f, 0.f, 0.f};
    acc[j] = z;
  }

  // x-tile ks: contiguous 10368B (648x16B) chunk -> LDS DMA; 1 DMA per thread
  // for tid<648.
  auto STAGE = [&](int ks) {
    const char* g = (const char*)xb + ks * 10368;
    char* lb = f32buf + (ks & 3) * 10368;
    if (tid < 648) GL16(g + tid * 16, lb + tid * 16);
  };

  // One transpose chunk: f32 [c][hw] tile t, chunk q (of 384) -> bf16 B-frag,
  // written at swizzled position q ^ ((q>>3)&3) (same map the reader uses).
  auto TRX = [&](int t, int q) {
    const float* src = (const float*)(f32buf + (t & 3) * 10368);
    char* dst = bfimg + (t & 3) * 6144;
    int nt_ = q >> 6, kr_ = (q >> 2) & 15, kg_ = q & 3;
    const float* s = src + kg_ * 648 + nt_ * 16 + kr_;
    uint4 v;
    v.x = cvtpk(s[0],   s[81]);
    v.y = cvtpk(s[162], s[243]);
    v.z = cvtpk(s[324], s[405]);
    v.w = cvtpk(s[486], s[567]);
    int qs = q ^ ((q >> 3) & 3);
    *(uint4*)(dst + qs * 16) = v;
  };
  // Two tiles (768 chunks) over 1024 threads: 1 chunk each for tid<768.
  auto TRANSPOSE2 = [&](int tA, int tB) {
    if (tid < 384)      TRX(tA, tid);
    else if (tid < 768) TRX(tB, tid - 384);
  };

  // ---- Prologue: stage tiles 0..3; build images 0,1 ------------------------
  // Tiles 2,3 deliberately stay IN FLIGHT into SUPER(0) (its af-wait retires
  // them before TRX(2,3) runs).
  STAGE(0); STAGE(1); STAGE(2); STAGE(3);             // <=4 DMA per wave
  asm volatile("s_waitcnt vmcnt(2)" ::: "memory");    // own D0,D1 landed
  __builtin_amdgcn_s_barrier();                       // all waves' D0,D1 landed
  __builtin_amdgcn_sched_barrier(0);
  TRANSPOSE2(0, 1);
  asm volatile("s_waitcnt lgkmcnt(0)" ::: "memory");  // images 0,1 visible
  __builtin_amdgcn_s_barrier();
  __builtin_amdgcn_sched_barrier(0);

  // Superstep s (tiles t0=2s, t1=2s+1): MFMA first, TRX after (see header).
  auto SUPER = [&](int s) {
    const int t0 = 2 * s, t1 = t0 + 1;
    short8 af0, af1;
    {
      const unsigned short* ab = wimg + w * 512 + kg * 128 + kr * 8;
      af0 = *(const short8*)(ab + t0 * 8192);
      af1 = *(const short8*)(ab + t1 * 8192);
    }
    __builtin_amdgcn_sched_barrier(0);      // pin af before the new DMAs
    if (s < 2) {
      STAGE(t0 + 4);                        // tiles 8,9 don't exist for s>=2
      STAGE(t1 + 4);
    }
    __builtin_amdgcn_sched_barrier(0);      // pin DMAs before MFMA region
    const char* bi0 = bfimg + (t0 & 3) * 6144;
    const char* bi1 = bfimg + (t1 & 3) * 6144;
    __builtin_amdgcn_s_setprio(1);
#pragma unroll
    for (int nt = 0; nt < 6; ++nt) {
      short8 bf = *(const short8*)(bi0 + nt * 1024 + fragoff);
      acc[nt] = __builtin_amdgcn_mfma_f32_16x16x32_bf16(af0, bf, acc[nt], 0, 0, 0);
    }
#pragma unroll
    for (int nt = 0; nt < 6; ++nt) {
      short8 bf = *(const short8*)(bi1 + nt * 1024 + fragoff);
      acc[nt] = __builtin_amdgcn_mfma_f32_16x16x32_bf16(af1, bf, acc[nt], 0, 0, 0);
    }
    __builtin_amdgcn_s_setprio(0);
    if (s < 3) {
      // stage(s-1) landed (retired by the compiler's af-wait); this explicit
      // wait is a no-op drain that ORDERS TRX's ds_reads after it while
      // leaving this superstep's 2 DMAs in flight.
      asm volatile("s_waitcnt vmcnt(2)" ::: "memory");
      __builtin_amdgcn_sched_barrier(0);
      TRANSPOSE2(t0 + 2, t1 + 2);
      asm volatile("s_waitcnt lgkmcnt(0)" ::: "memory"); // new images visible
      __builtin_amdgcn_s_barrier();
      __builtin_amdgcn_sched_barrier(0);
    } else {
      __syncthreads();                      // full fence before pT overlays
    }
  };

  SUPER(0); SUPER(1); SUPER(2); SUPER(3);

  // ---------------- BN+ReLU -> pT (bf16, GEMM-2 B-frag layout) + p_mean -----
  {
    int ob = w * 16 + g4;
    float sc0 = s_scale[ob], sc1 = s_scale[ob + 1], sc2 = s_scale[ob + 2], sc3 = s_scale[ob + 3];
    float bi0 = s_bias[ob],  bi1 = s_bias[ob + 1],  bi2 = s_bias[ob + 2],  bi3 = s_bias[ob + 3];
    float vs0 = 0.f, vs1 = 0.f, vs2 = 0.f, vs3 = 0.f;
    int ks2 = ob >> 5;
    int j2  = (ob >> 3) & 3;
    int e0  = ob & 7;
    char* pbase = (char*)pT + ks2 * 6144 + j2 * 256 + kr * 16 + e0 * 2;
#pragma unroll
    for (int nt = 0; nt < 6; ++nt) {
      float v0 = fmaxf(acc[nt][0] * sc0 + bi0, 0.f);
      float v1 = fmaxf(acc[nt][1] * sc1 + bi1, 0.f);
      float v2 = fmaxf(acc[nt][2] * sc2 + bi2, 0.f);
      float v3 = fmaxf(acc[nt][3] * sc3 + bi3, 0.f);
      if (nt < 5 || kr == 0) { vs0 += v0; vs1 += v1; vs2 += v2; vs3 += v3; } // hw<=80
      uint2 pvv;
      pvv.x = cvtpk(v0, v1);
      pvv.y = cvtpk(v2, v3);
      *(uint2*)(pbase + nt * 1024) = pvv;
    }
    float vv[4] = {vs0, vs1, vs2, vs3};
#pragma unroll
    for (int i = 0; i < 4; ++i) {
      float s = vv[i];
      s += __shfl_xor(s, 1);
      s += __shfl_xor(s, 2);
      s += __shfl_xor(s, 4);
      s += __shfl_xor(s, 8);
      vv[i] = s;
    }
    if (kr == 0) {
      s_pmean[ob]     = vv[0] * (1.f / 81.f);
      s_pmean[ob + 1] = vv[1] * (1.f / 81.f);
      s_pmean[ob + 2] = vv[2] * (1.f / 81.f);
      s_pmean[ob + 3] = vv[3] * (1.f / 81.f);
    }
  }
  __syncthreads();   // pT + s_pmean visible

  // ---------------- Split phase: waves 0-11 GEMM-2 | waves 12-15 masks+heads
  const int* amr = am + (size_t)b * ACT;
  const int mt12 = w & 1;        // for w<12
  const int nt12 = w >> 1;       // 0..5
  f32x4 acc2 = {0.f, 0.f, 0.f, 0.f};

  if (w < 12) {
    // GEMM-2: one (mt,nt) pair per wave; 8 MFMA + 8 b128 LDS reads
#pragma unroll
    for (int ks2 = 0; ks2 < 8; ++ks2) {
      const unsigned short* ap = w2img + ((ks2 * 2 + mt12) * 4 + kg) * 128 + kr * 8;
      short8 a2 = *(const short8*)ap;
      const short8* bp = (const short8*)((const char*)pT + ks2 * 6144 + nt12 * 1024 + kg * 256 + kr * 16);
      acc2 = __builtin_amdgcn_mfma_f32_16x16x32_bf16(a2, *bp, acc2, 0, 0, 0);
    }
  } else {
    // waves 12-15: issue amr loads first, head dots while in flight, then
    // ballots (use forces the wait).
    const int t0 = w - 12;               // 0..3
    int va[7], vb[7];
#pragma unroll
    for (int i = 0; i < 7; ++i) {
      int t = t0 + 4 * i;
      va[i] = 0; vb[i] = 0;
      if (t < 25) {
        int off = (t < 24) ? (82 + t * 81) : 1;
        va[i] = amr[off + l];
        vb[i] = (l < 17) ? amr[off + 64 + l] : 0;
      }
    }
    // head partial dots (30 heads x 8 segments = 240 units on waves 12-15)
    int hh = tid - 768;
    if (hh < 240) {
      int h = hh >> 3, seg = hh & 7;
      const float* wp = (h < 3) ? (type_w + h * 256)
                      : (h < 6) ? (slot_w + (h - 3) * 256)
                                : (orient_w + (h - 6) * 256);
      float p = 0.f;
      int base = seg * 32;
#pragma unroll 8
      for (int e = 0; e < 32; ++e) p += s_pmean[base + e] * wp[base + e];
      s_part[hh] = p;
    }
    // ballots
#pragma unroll
    for (int i = 0; i < 7; ++i) {
      int t = t0 + 4 * i;
      if (t < 25) {
        unsigned long long bal = __ballot((va[i] | vb[i]) != 0);
        if (l == 0) {
          int any = (bal != 0ULL) ? 1 : 0;
          if (t < 24) s_omask[t] = any; else s_misc[0] = any;
        }
      }
    }
  }
  __syncthreads();   // pT reads done; s_part/s_omask/s_misc visible

  // -------- P4: s_out2 (overlays pT) + head combine + slot/buy any-masks ----
  if (w < 12) {
    int hw = nt12 * 16 + kr;
    int m2 = mt12 * 16 + g4;
#pragma unroll
    for (int i = 0; i < 4; ++i)
      s_out2[(m2 + i) * 104 + hw] = acc2[i];
  }
  if (tid < 30) {
    float a = 0.f;
#pragma unroll
    for (int e = 0; e < 8; ++e) a += s_part[tid * 8 + e];
    a += (tid < 3) ? type_b[tid] : (tid < 6) ? slot_b[tid - 3] : orient_b[tid - 6];
    s_hl[tid] = a;
  }
  if (tid == 32) {
    int sa0 = 0, sa1 = 0, sa2 = 0;
#pragma unroll
    for (int rr = 0; rr < 8; ++rr) { sa0 |= s_omask[rr]; sa1 |= s_omask[8 + rr]; sa2 |= s_omask[16 + rr]; }
    s_misc[1] = sa0; s_misc[2] = sa1; s_misc[3] = sa2;
    s_misc[4] = sa0 | sa1 | sa2;
  }
  __syncthreads();

  // -------- P6: per-thread small softmaxes (broadcast LDS reads) + 81-wide --
  float tlp0, tlp1, tlp2;
  {
    int mk0 = amr[0] > 0, mk1 = s_misc[0], mk2 = s_misc[4];
    float g0 = mk0 ? s_hl[0] : NEGV;
    float g1 = mk1 ? s_hl[1] : NEGV;
    float g2 = mk2 ? s_hl[2] : NEGV;
    float m = fmaxf(fmaxf(g0, g1), g2);
    float ls = m + __logf(__expf(g0 - m) + __expf(g1 - m) + __expf(g2 - m));
    tlp0 = fmaxf(g0 - ls, -100.f);
    tlp1 = fmaxf(g1 - ls, -100.f);
    tlp2 = fmaxf(g2 - ls, -100.f);
  }
  float slp[3];
  {
    float g[3]; float m = -3.0e38f;
#pragma unroll
    for (int s = 0; s < 3; ++s) { g[s] = s_misc[1 + s] ? s_hl[3 + s] : NEGV; m = fmaxf(m, g[s]); }
    float sum = 0.f;
#pragma unroll
    for (int s = 0; s < 3; ++s) sum += __expf(g[s] - m);
    float ls = m + __logf(sum);
#pragma unroll
    for (int s = 0; s < 3; ++s) slp[s] = fmaxf(g[s] - ls, -100.f);
  }

  float* ob_out = out + (size_t)b * ACT;
  for (int t = w; t < 25; t += 16) {
    int off = (t < 24) ? (82 + t * 81) : 1;
    float badd = (t < 24) ? pos_b[t] : patch_b[0];
    int a1 = amr[off + l];
    int a2v = (l < 17) ? amr[off + 64 + l] : 0;
    float lg1 = (a1 > 0) ? (s_out2[t * 104 + l] + badd) : NEGV;
    float lg2 = (l < 17 && a2v > 0) ? (s_out2[t * 104 + 64 + l] + badd) : NEGV;
    float mx = fmaxf(lg1, (l < 17) ? lg2 : -3.0e38f);
#pragma unroll
    for (int mm = 1; mm < 64; mm <<= 1) mx = fmaxf(mx, __shfl_xor(mx, mm));
    float sm = __expf(lg1 - mx) + ((l < 17) ? __expf(lg2 - mx) : 0.f);
#pragma unroll
    for (int mm = 1; mm < 64; mm <<= 1) sm += __shfl_xor(sm, mm);
    float lse = mx + __logf(sm);
    float lp1 = fmaxf(lg1 - lse, -100.f);
    float lp2 = fmaxf(lg2 - lse, -100.f);
    float addj; int obase;
    if (t < 24) {
      int sl = t >> 3;
      float g[8]; float m = -3.0e38f;
#pragma unroll
      for (int rr = 0; rr < 8; ++rr) {
        g[rr] = s_omask[sl * 8 + rr] ? s_hl[6 + sl * 8 + rr] : NEGV;
        m = fmaxf(m, g[rr]);
      }
      float sum = 0.f;
#pragma unroll
      for (int rr = 0; rr < 8; ++rr) sum += __expf(g[rr] - m);
      float ls = m + __logf(sum);
      float olp_t = fmaxf(g[t & 7] - ls, -100.f);
      addj = tlp2 + slp[sl] + olp_t;
      obase = 82 + t * 81;
    } else {
      addj = tlp1;
      obase = 1;
    }
    ob_out[obase + l] = addj + lp1;
    if (l < 17) ob_out[obase + 64 + l] = addj + lp2;
    if (t == 24 && l == 0) ob_out[0] = tlp0;
  }
}

// ---------------------------------------------------------------------------
extern "C" void kernel_launch(void* const* d_in, const int* in_sizes, int n_in,
                              void* d_out, int out_size, void* d_ws, size_t ws_size,
                              hipStream_t stream) {
  (void)in_sizes; (void)n_in; (void)out_size; (void)ws_size;
  const float* x        = (const float*)d_in[0];
  const int*   amask    = (const int*)d_in[1];
  const float* conv_w   = (const float*)d_in[2];
  const float* bn_gamma = (const float*)d_in[3];
  const float* bn_beta  = (const float*)d_in[4];
  const float* bn_mean  = (const float*)d_in[5];
  const float* bn_var   = (const float*)d_in[6];
  const float* type_w   = (const float*)d_in[7];
  const float* type_b   = (const float*)d_in[8];
  const float* patch_w  = (const float*)d_in[9];
  const float* patch_b  = (const float*)d_in[10];
  const float* slot_w   = (const float*)d_in[11];
  const float* slot_b   = (const float*)d_in[12];
  const float* orient_w = (const float*)d_in[13];
  const float* orient_b = (const float*)d_in[14];
  const float* pos_w    = (const float*)d_in[15];
  const float* pos_b    = (const float*)d_in[16];
  float* outp = (float*)d_out;

  unsigned short* wimg  = (unsigned short*)d_ws;         // 131072 B
  unsigned short* w2img = wimg + 65536;                  // 16384 B

  prep_w_kernel<<<36, 256, 0, stream>>>(conv_w, pos_w, patch_w, wimg, w2img);
  policy_main<<<4096, 1024, 0, stream>>>(x, amask, wimg, w2img,
                                         bn_gamma, bn_beta, bn_mean, bn_var,
                                         type_w, type_b, patch_b,
                                         slot_w, slot_b, orient_w, orient_b,
                                         pos_b, outp);
}